// Round 5
// baseline (1982.332 us; speedup 1.0000x reference)
//
#include <hip/hip_runtime.h>

__global__ void k_fill(unsigned* p, int n, unsigned v) {
    int i = blockIdx.x * blockDim.x + threadIdx.x;
    if (i < n) p[i] = v;
}

// ---------------- CSR build (graph identical across layers; built once) ----------------
__global__ void k_hist(const int* __restrict__ ei, int E, int* __restrict__ deg) {
    int e = blockIdx.x * blockDim.x + threadIdx.x;
    if (e < E) atomicAdd(&deg[ei[E + e]], 1);
}

__global__ void k_scan_blocks(const int* __restrict__ deg, int N,
                              int* __restrict__ excl, int* __restrict__ parts) {
    __shared__ int s[256];
    int t = threadIdx.x, i = blockIdx.x * 256 + t;
    int v = (i < N) ? deg[i] : 0;
    s[t] = v;
    __syncthreads();
    int acc = v;
    for (int off = 1; off < 256; off <<= 1) {
        int add = (t >= off) ? s[t - off] : 0;
        __syncthreads();
        acc += add;
        s[t] = acc;
        __syncthreads();
    }
    if (i < N) excl[i] = acc - v;
    if (t == 255) parts[blockIdx.x] = acc;
}

__global__ void k_scan_parts(int* __restrict__ parts, int nb) {
    __shared__ int s[256];
    int t = threadIdx.x;
    int v = (t < nb) ? parts[t] : 0;
    s[t] = v;
    __syncthreads();
    int acc = v;
    for (int off = 1; off < 256; off <<= 1) {
        int add = (t >= off) ? s[t - off] : 0;
        __syncthreads();
        acc += add;
        s[t] = acc;
        __syncthreads();
    }
    if (t < nb) parts[t] = acc - v;
}

__global__ void k_scan_add(const int* __restrict__ excl, const int* __restrict__ parts,
                           int* __restrict__ row_ptr, int* __restrict__ cursor, int N) {
    int i = blockIdx.x * blockDim.x + threadIdx.x;
    if (i >= N) return;
    int r = excl[i] + parts[i >> 8];
    row_ptr[i] = r;
    cursor[i] = r;
}

__global__ void k_scatter(const int* __restrict__ ei, int E, int* __restrict__ cursor,
                          int* __restrict__ esrc, int* __restrict__ eeid) {
    int e = blockIdx.x * blockDim.x + threadIdx.x;
    if (e >= E) return;
    int d = ei[E + e];
    int j = atomicAdd(&cursor[d], 1);
    esrc[j] = ei[e];
    eeid[j] = e;
}

// fill edst[slot] = dst node (CSR ranges, one thread per node)
__global__ void k_dstfill(const int* __restrict__ row_ptr, const int* __restrict__ deg,
                          int* __restrict__ edst, int N) {
    int n = blockIdx.x * blockDim.x + threadIdx.x;
    if (n >= N) return;
    int s = row_ptr[n], d = deg[n];
    for (int i = 0; i < d; i++) edst[s + i] = n;
}

// ---------------- Dual GEMM: out{l,r} = A @ W{l,r} + b{l,r} ----------------
template <int M, int RW>
__global__ __launch_bounds__(256) void k_gemm2(const float* __restrict__ A,
                                               const float* __restrict__ Wl, const float* __restrict__ bl,
                                               const float* __restrict__ Wr, const float* __restrict__ br,
                                               float* __restrict__ outl, float* __restrict__ outr) {
    constexpr int TX = M / 4;
    __shared__ float sA[32][68];
    __shared__ float sW[32][M];
    const float* W    = blockIdx.y ? Wr : Wl;
    const float* bias = blockIdx.y ? br : bl;
    float* out        = blockIdx.y ? outr : outl;
    int t = threadIdx.x;
    int tx = t % TX, ty = t / TX;
    int r0 = blockIdx.x * 64;
    float acc[RW][4] = {};
    for (int kt = 0; kt < 128; kt += 32) {
        for (int l = t; l < 512; l += 256) {
            int row = l >> 3, kq = (l & 7) << 2;
            float4 a = *(const float4*)&A[(size_t)(r0 + row) * 128 + kt + kq];
            sA[kq + 0][row] = a.x; sA[kq + 1][row] = a.y;
            sA[kq + 2][row] = a.z; sA[kq + 3][row] = a.w;
        }
        for (int l = t; l < 32 * M / 4; l += 256) {
            int kk = (l * 4) / M, cc = (l * 4) % M;
            *(float4*)&sW[kk][cc] = *(const float4*)&W[(size_t)(kt + kk) * M + cc];
        }
        __syncthreads();
#pragma unroll
        for (int k = 0; k < 32; k++) {
            float4 w = *(float4*)&sW[k][tx * 4];
            float ar[RW];
#pragma unroll
            for (int i = 0; i < RW; i += 4) {
                float4 a = *(float4*)&sA[k][ty * RW + i];
                ar[i] = a.x; ar[i + 1] = a.y; ar[i + 2] = a.z; ar[i + 3] = a.w;
            }
#pragma unroll
            for (int i = 0; i < RW; i++) {
                acc[i][0] += ar[i] * w.x; acc[i][1] += ar[i] * w.y;
                acc[i][2] += ar[i] * w.z; acc[i][3] += ar[i] * w.w;
            }
        }
        __syncthreads();
    }
    float4 b = *(const float4*)&bias[tx * 4];
#pragma unroll
    for (int i = 0; i < RW; i++) {
        float4 v;
        v.x = acc[i][0] + b.x; v.y = acc[i][1] + b.y;
        v.z = acc[i][2] + b.z; v.w = acc[i][3] + b.w;
        *(float4*)&out[(size_t)(r0 + ty * RW + i) * M + tx * 4] = v;
    }
}

// ---------------- Edge logit kernel: per CSR slot s, per head h ----------------
// logit[s,h] = sum_c att[h,c] * leaky( xl[src,c] + xr[dst,c] + (ea[eid] @ We)[c] )
// 512 threads / 64 slots per block: RW=4 (HC=128) / 2 (HC=64) rows per thread keeps
// acc + epilogue liveness small (round-4's 256-thread RW=8 version hit VGPR=220 ->
// 11.5% occupancy, latency-bound). GEMM on transposed-LDS float4 reads; epilogue
// gathers xl/xr coalesced float4 and shuffle-reduces per 16-lane head group.
// Writes 4-8 B/edge instead of materializing the 512B ee row.
template <int HC>
__global__ __launch_bounds__(512) void k_elogit(const float* __restrict__ ea,
                                                const int* __restrict__ eeid,
                                                const int* __restrict__ esrc,
                                                const int* __restrict__ edst,
                                                const float* __restrict__ We,
                                                const float* __restrict__ att,
                                                const float* __restrict__ xl,
                                                const float* __restrict__ xr,
                                                float* __restrict__ logit, int E) {
    constexpr int ROWS = 64;
    constexpr int TX = HC / 4;             // 32 (HC=128) or 16 (HC=64)
    constexpr int RW = ROWS / (512 / TX);  // 4 or 2
    __shared__ float sA[32][ROWS + 4];     // k-major: sA[k][row]
    __shared__ float sW[32][HC];
    int sb = blockIdx.x * ROWS;
    if (sb >= E) return;
    int t = threadIdx.x;
    for (int l = t; l < ROWS * 8; l += 512) {
        int row = l >> 3, kq = (l & 7) << 2;
        int s = sb + row;
        int eid = (s < E) ? eeid[s] : 0;
        float4 a = *(const float4*)&ea[(size_t)eid * 32 + kq];
        sA[kq + 0][row] = a.x; sA[kq + 1][row] = a.y;
        sA[kq + 2][row] = a.z; sA[kq + 3][row] = a.w;
    }
    for (int l = t; l < 32 * HC / 4; l += 512) {
        int k = (l * 4) / HC, c = (l * 4) % HC;
        *(float4*)&sW[k][c] = *(const float4*)&We[k * HC + c];
    }
    __syncthreads();
    int tx = t % TX, ty = t / TX;
    float4 attv = *(const float4*)&att[tx * 4];
    float acc[RW][4] = {};
#pragma unroll
    for (int k = 0; k < 32; k++) {
        float4 w = *(float4*)&sW[k][tx * 4];
        float ar[RW];
#pragma unroll
        for (int i = 0; i < RW; i++) ar[i] = sA[k][ty * RW + i];
#pragma unroll
        for (int i = 0; i < RW; i++) {
            acc[i][0] = fmaf(ar[i], w.x, acc[i][0]);
            acc[i][1] = fmaf(ar[i], w.y, acc[i][1]);
            acc[i][2] = fmaf(ar[i], w.z, acc[i][2]);
            acc[i][3] = fmaf(ar[i], w.w, acc[i][3]);
        }
    }
#pragma unroll
    for (int i = 0; i < RW; i++) {
        int s = sb + ty * RW + i;
        bool ok = s < E;
        int src = ok ? esrc[s] : 0;
        int dst = ok ? edst[s] : 0;
        float4 xl4 = *(const float4*)&xl[(size_t)src * HC + tx * 4];
        float4 xr4 = *(const float4*)&xr[(size_t)dst * HC + tx * 4];
        float v0 = acc[i][0] + xl4.x + xr4.x; v0 = v0 > 0.f ? v0 : 0.2f * v0;
        float v1 = acc[i][1] + xl4.y + xr4.y; v1 = v1 > 0.f ? v1 : 0.2f * v1;
        float v2 = acc[i][2] + xl4.z + xr4.z; v2 = v2 > 0.f ? v2 : 0.2f * v2;
        float v3 = acc[i][3] + xl4.w + xr4.w; v3 = v3 > 0.f ? v3 : 0.2f * v3;
        float p = fmaf(attv.x, v0, fmaf(attv.y, v1, fmaf(attv.z, v2, attv.w * v3)));
#pragma unroll
        for (int m = 1; m < 16; m <<= 1) p += __shfl_xor(p, m);
        if constexpr (HC == 128) {
            if ((tx & 15) == 0 && ok) logit[2 * (size_t)s + (tx >> 4)] = p;
        } else {
            if (tx == 0 && ok) logit[s] = p;
        }
    }
}

// ---------------- Lean aggregation using precomputed logits ----------------
// Per visit: esrc (4B), logit (broadcast), xl float2 (coalesced 512B/wave), exp, 2 FMA.
// No shuffle butterfly, no We, no ea. Block = 4 waves = 2 nodes x 2 edge-parity waves.
// H==2: lane-half = head. H==1: lane-half = extra edge parity (4 edges in flight/wave-pair).
template <int H, bool RELU>
__global__ __launch_bounds__(256) void k_aggv(const float* __restrict__ xl,
                                              const float* __restrict__ logit,
                                              const int* __restrict__ esrc,
                                              const int* __restrict__ row_ptr, const int* __restrict__ deg,
                                              const float* __restrict__ bias,
                                              float* __restrict__ out, int N) {
    constexpr int HC = H * 64;
    __shared__ float2 sAcc[2][64];
    __shared__ float  sDen[2][64];
    int tid = threadIdx.x, wv = tid >> 6, lane = tid & 63;
    int ns = wv >> 1, eh = wv & 1;
    int n = blockIdx.x * 2 + ns;
    bool alive = n < N;
    int hf = lane >> 5, c2 = lane & 31;
    int col = (H == 2) ? (hf * 64 + 2 * c2) : (2 * c2);
    int start = 0, d = 0;
    if (alive) { start = row_ptr[n]; d = deg[n]; }
    float2 acc = make_float2(0.f, 0.f);
    float den = 0.f;
    const int jstep = (H == 2) ? 2 : 4;
    int jc = (H == 2) ? eh : (2 * eh + hf);

    bool okc = jc < d;
    int sC = start + jc, sN = sC + jstep;
    float lgC = 0.f;
    float2 xlC = make_float2(0.f, 0.f);
    if (okc) {
        lgC = (H == 2) ? logit[2 * (size_t)sC + hf] : logit[sC];
        xlC = *(const float2*)&xl[(size_t)esrc[sC] * HC + col];
    }
    bool okn = (jc + jstep) < d;
    while (okc) {
        float lgN = 0.f;
        float2 xlN = make_float2(0.f, 0.f);
        if (okn) {
            lgN = (H == 2) ? logit[2 * (size_t)sN + hf] : logit[sN];
            xlN = *(const float2*)&xl[(size_t)esrc[sN] * HC + col];
        }
        float ex = __expf(lgC);
        acc.x = fmaf(ex, xlC.x, acc.x);
        acc.y = fmaf(ex, xlC.y, acc.y);
        den += ex;
        jc += jstep; sC = sN; sN += jstep;
        lgC = lgN; xlC = xlN;
        okc = okn; okn = (jc + jstep) < d;
    }

    if constexpr (H == 1) {   // halves hold disjoint edge subsets of same channels
        acc.x += __shfl_xor(acc.x, 32);
        acc.y += __shfl_xor(acc.y, 32);
        den   += __shfl_xor(den, 32);
    }
    if (eh == 1) { sAcc[ns][lane] = acc; sDen[ns][lane] = den; }
    __syncthreads();
    if (eh == 0 && alive) {
        float2 a2 = sAcc[ns][lane];
        float dsum = den + sDen[ns][lane] + 1e-16f;
        float2 bv = *(const float2*)&bias[col];
        float o0 = (acc.x + a2.x) / dsum + bv.x;
        float o1 = (acc.y + a2.y) / dsum + bv.y;
        if (RELU) { o0 = fmaxf(o0, 0.f); o1 = fmaxf(o1, 0.f); }
        if (H == 2 || hf == 0)
            *(float2*)&out[(size_t)n * HC + col] = make_float2(o0, o1);
    }
}

// ---------------- Fallback agg (round-0 structure) — tiny-workspace path ----------------
template <int H, bool RELU>
__global__ __launch_bounds__(256) void k_agg_fb(const float* __restrict__ xl, const float* __restrict__ xr,
                                                const float* __restrict__ ea,
                                                const int* __restrict__ esrc, const int* __restrict__ eeid,
                                                const int* __restrict__ row_ptr, const int* __restrict__ deg,
                                                const float* __restrict__ We, const float* __restrict__ att,
                                                const float* __restrict__ bias, float* __restrict__ out, int N) {
    constexpr int HC = H * 64;
    int tid = threadIdx.x, wv = tid >> 6, lane = tid & 63;
    float rWe0[32], rWe1[H == 2 ? 32 : 1];
#pragma unroll
    for (int k = 0; k < 32; k++) rWe0[k] = We[k * HC + lane];
    if constexpr (H == 2) {
#pragma unroll
        for (int k = 0; k < 32; k++) rWe1[k] = We[k * HC + 64 + lane];
    }
    float att0 = att[lane], b0 = bias[lane];
    float att1 = 0.f, b1 = 0.f;
    if constexpr (H == 2) { att1 = att[64 + lane]; b1 = bias[64 + lane]; }
    int n = blockIdx.x * 4 + wv;
    if (n >= N) return;
    int start = row_ptr[n], d = deg[n];
    float xr0 = xr[(size_t)n * HC + lane];
    float xr1 = (H == 2) ? xr[(size_t)n * HC + 64 + lane] : 0.f;
    float acc0 = 0.f, acc1 = 0.f, den0 = 0.f, den1 = 0.f;
    for (int j = 0; j < d; j++) {
        int src = esrc[start + j], eid = eeid[start + j];
        const float4* eap = (const float4*)(ea + (size_t)eid * 32);
        const float* xls = xl + (size_t)src * HC;
        float xl0 = xls[lane];
        float xl1 = (H == 2) ? xls[64 + lane] : 0.f;
        float ee0 = 0.f, ee1 = 0.f;
#pragma unroll
        for (int kq = 0; kq < 8; kq++) {
            float4 v = eap[kq];
            ee0 = fmaf(v.x, rWe0[kq * 4 + 0], ee0);
            ee0 = fmaf(v.y, rWe0[kq * 4 + 1], ee0);
            ee0 = fmaf(v.z, rWe0[kq * 4 + 2], ee0);
            ee0 = fmaf(v.w, rWe0[kq * 4 + 3], ee0);
            if constexpr (H == 2) {
                ee1 = fmaf(v.x, rWe1[kq * 4 + 0], ee1);
                ee1 = fmaf(v.y, rWe1[kq * 4 + 1], ee1);
                ee1 = fmaf(v.z, rWe1[kq * 4 + 2], ee1);
                ee1 = fmaf(v.w, rWe1[kq * 4 + 3], ee1);
            }
        }
        float v0 = xl0 + xr0 + ee0;
        v0 = v0 > 0.f ? v0 : 0.2f * v0;
        float p0 = att0 * v0, p1 = 0.f;
        if constexpr (H == 2) {
            float v1 = xl1 + xr1 + ee1;
            v1 = v1 > 0.f ? v1 : 0.2f * v1;
            p1 = att1 * v1;
        }
#pragma unroll
        for (int m = 32; m; m >>= 1) {
            p0 += __shfl_xor(p0, m);
            if constexpr (H == 2) p1 += __shfl_xor(p1, m);
        }
        float ex0 = __expf(p0);
        acc0 = fmaf(ex0, xl0, acc0);
        den0 += ex0;
        if constexpr (H == 2) {
            float ex1 = __expf(p1);
            acc1 = fmaf(ex1, xl1, acc1);
            den1 += ex1;
        }
    }
    float o0 = acc0 / (den0 + 1e-16f) + b0;
    if (RELU) o0 = o0 > 0.f ? o0 : 0.f;
    out[(size_t)n * HC + lane] = o0;
    if constexpr (H == 2) {
        float o1 = acc1 / (den1 + 1e-16f) + b1;
        if (RELU) o1 = o1 > 0.f ? o1 : 0.f;
        out[(size_t)n * HC + 64 + lane] = o1;
    }
}

// ---------------- gate MLP ----------------
__global__ __launch_bounds__(256) void k_gate(const float* __restrict__ h, const float* __restrict__ G1w,
                                              const float* __restrict__ G1b, const float* __restrict__ G2w,
                                              const float* __restrict__ G2b,
                                              float* __restrict__ gate, int N) {
    __shared__ float sH[64][64];
    __shared__ float part[64][2];
    int t = threadIdx.x;
    int n0 = blockIdx.x * 64;
    for (int l = t; l < 1024; l += 256) {
        float4 v = ((const float4*)(h + (size_t)n0 * 64))[l];
        int n = l >> 4, kq = (l & 15) << 2;
        *(float4*)&sH[n][kq] = v;
    }
    int c = t & 127, half = t >> 7;
    float rW[64];
#pragma unroll
    for (int k = 0; k < 64; k++) rW[k] = G1w[k * 128 + c];
    float g1b = G1b[c], g2w = G2w[c];
    __syncthreads();
    for (int nn = 0; nn < 32; nn++) {
        int n = half * 32 + nn;
        float acc = g1b;
#pragma unroll
        for (int k = 0; k < 64; k += 4) {
            float4 hv = *(const float4*)&sH[n][k];
            acc = fmaf(hv.x, rW[k], acc);
            acc = fmaf(hv.y, rW[k + 1], acc);
            acc = fmaf(hv.z, rW[k + 2], acc);
            acc = fmaf(hv.w, rW[k + 3], acc);
        }
        acc = acc > 0.f ? acc : 0.f;
        float p = acc * g2w;
#pragma unroll
        for (int m = 32; m; m >>= 1) p += __shfl_xor(p, m);
        if ((t & 63) == 0) part[n][(t >> 6) & 1] = p;
    }
    __syncthreads();
    if (t < 64) gate[n0 + t] = __expf(part[t][0] + part[t][1] + G2b[0]);
}

// ---------------- pooling ----------------
__global__ __launch_bounds__(256) void k_pool(const float* __restrict__ h, const float* __restrict__ gate,
                                              const int* __restrict__ batch,
                                              float* __restrict__ pooled, int N) {
    int g = blockIdx.x;
    int lo = 0, hi = N;
    while (lo < hi) { int mid = (lo + hi) >> 1; if (batch[mid] < g) lo = mid + 1; else hi = mid; }
    int start = lo;
    lo = 0; hi = N;
    while (lo < hi) { int mid = (lo + hi) >> 1; if (batch[mid] < g + 1) lo = mid + 1; else hi = mid; }
    int end = lo;
    int t = threadIdx.x, wv = t >> 6, lane = t & 63;
    float acc = 0.f, den = 0.f;
    for (int n = start + wv; n < end; n += 4) {
        float gv = gate[n];
        acc = fmaf(gv, h[(size_t)n * 64 + lane], acc);
        den += gv;
    }
    __shared__ float sacc[4][64];
    __shared__ float sden[4];
    sacc[wv][lane] = acc;
    if (lane == 0) sden[wv] = den;
    __syncthreads();
    if (wv == 0) {
        float a = sacc[0][lane] + sacc[1][lane] + sacc[2][lane] + sacc[3][lane];
        float d = sden[0] + sden[1] + sden[2] + sden[3] + 1e-16f;
        pooled[g * 64 + lane] = a / d;
    }
}

__global__ void k_final(const float* __restrict__ pooled, const float* __restrict__ Wreg,
                        const float* __restrict__ breg, float* __restrict__ out) {
    int g = threadIdx.x;
    float acc = breg[0];
    for (int c = 0; c < 64; c++) acc += pooled[g * 64 + c] * Wreg[c];
    out[g] = acc;
}

extern "C" void kernel_launch(void* const* d_in, const int* in_sizes, int n_in,
                              void* d_out, int out_size, void* d_ws, size_t ws_size,
                              hipStream_t stream) {
    const float* x  = (const float*)d_in[0];
    const float* ea = (const float*)d_in[1];
    const int* ei    = (const int*)d_in[2];
    const int* batch = (const int*)d_in[3];
    auto ff = [&](int i) { return (const float*)d_in[i]; };
    const float *W1l = ff(4), *b1l = ff(5), *W1r = ff(6), *b1r = ff(7), *W1e = ff(8),
                *att1 = ff(9), *bias1 = ff(10);
    const float *W2l = ff(11), *b2l = ff(12), *W2r = ff(13), *b2r = ff(14), *W2e = ff(15),
                *att2 = ff(16), *bias2 = ff(17);
    const float *W3l = ff(18), *b3l = ff(19), *W3r = ff(20), *b3r = ff(21), *W3e = ff(22),
                *att3 = ff(23), *bias3 = ff(24);
    const float *G1w = ff(25), *G1b = ff(26), *G2w = ff(27), *G2b = ff(28), *Wreg = ff(29),
                *breg = ff(30);

    const int N = in_sizes[0] / 128;  // 40000
    const int E = in_sizes[2] / 2;    // 640000

    char* ws = (char*)d_ws;
    float*  bufA    = (float*)(ws);              // [N,128]
    float*  bufB    = (float*)(ws + 20480000);   // [N,128]
    float*  bufH    = (float*)(ws + 40960000);   // [N,128]
    int*    esrc    = (int*)(ws + 61440000);     // [E]
    int*    eeid    = (int*)(ws + 64000000);     // [E]
    int*    row_ptr = (int*)(ws + 66560000);     // [N]
    int*    deg     = (int*)(ws + 66720000);     // [N]
    int*    cursor  = (int*)(ws + 66880000);     // [N]
    int*    excl    = (int*)(ws + 67040000);     // [N]
    int*    parts   = (int*)(ws + 67200000);     // [<=256]
    float*  gate    = (float*)(ws + 67204096);   // [N]
    float*  pooled  = (float*)(ws + 67364096);   // [64,64]
    int*    edst    = (int*)(ws + 67380480);     // [E]
    float*  logit   = (float*)(ws + 69940480);   // [E,2]
    const bool newpath = ws_size >= (size_t)69940480 + (size_t)E * 2 * 4;

    auto cdiv = [](int a, int b) { return (a + b - 1) / b; };
    const int NB = cdiv(N, 256);
    const dim3 gemmG(N / 64, 2);
    const int ELB = cdiv(E, 64);
    const int AGB = cdiv(N, 2);

    // ---- CSR build (once; graph shared by all 3 layers) ----
    k_fill<<<NB, 256, 0, stream>>>((unsigned*)deg, N, 0u);
    k_hist<<<cdiv(E, 256), 256, 0, stream>>>(ei, E, deg);
    k_scan_blocks<<<NB, 256, 0, stream>>>(deg, N, excl, parts);
    k_scan_parts<<<1, 256, 0, stream>>>(parts, NB);
    k_scan_add<<<NB, 256, 0, stream>>>(excl, parts, row_ptr, cursor, N);
    k_scatter<<<cdiv(E, 256), 256, 0, stream>>>(ei, E, cursor, esrc, eeid);

    if (newpath) {
        k_dstfill<<<NB, 256, 0, stream>>>(row_ptr, deg, edst, N);
        // ---- layer 1 ----
        k_gemm2<128, 8><<<gemmG, 256, 0, stream>>>(x, W1l, b1l, W1r, b1r, bufA, bufB);
        k_elogit<128><<<ELB, 512, 0, stream>>>(ea, eeid, esrc, edst, W1e, att1, bufA, bufB, logit, E);
        k_aggv<2, true><<<AGB, 256, 0, stream>>>(bufA, logit, esrc, row_ptr, deg, bias1, bufH, N);
        // ---- layer 2 ----
        k_gemm2<128, 8><<<gemmG, 256, 0, stream>>>(bufH, W2l, b2l, W2r, b2r, bufA, bufB);
        k_elogit<128><<<ELB, 512, 0, stream>>>(ea, eeid, esrc, edst, W2e, att2, bufA, bufB, logit, E);
        k_aggv<2, true><<<AGB, 256, 0, stream>>>(bufA, logit, esrc, row_ptr, deg, bias2, bufH, N);
        // ---- layer 3 ----
        k_gemm2<64, 4><<<gemmG, 256, 0, stream>>>(bufH, W3l, b3l, W3r, b3r, bufA, bufB);
        k_elogit<64><<<ELB, 512, 0, stream>>>(ea, eeid, esrc, edst, W3e, att3, bufA, bufB, logit, E);
        k_aggv<1, false><<<AGB, 256, 0, stream>>>(bufA, logit, esrc, row_ptr, deg, bias3, bufH, N);
    } else {
        const int AGGB = cdiv(N, 4);
        k_gemm2<128, 8><<<gemmG, 256, 0, stream>>>(x, W1l, b1l, W1r, b1r, bufA, bufB);
        k_agg_fb<2, true><<<AGGB, 256, 0, stream>>>(bufA, bufB, ea, esrc, eeid, row_ptr, deg, W1e, att1, bias1, bufH, N);
        k_gemm2<128, 8><<<gemmG, 256, 0, stream>>>(bufH, W2l, b2l, W2r, b2r, bufA, bufB);
        k_agg_fb<2, true><<<AGGB, 256, 0, stream>>>(bufA, bufB, ea, esrc, eeid, row_ptr, deg, W2e, att2, bias2, bufH, N);
        k_gemm2<64, 4><<<gemmG, 256, 0, stream>>>(bufH, W3l, b3l, W3r, b3r, bufA, bufB);
        k_agg_fb<1, false><<<AGGB, 256, 0, stream>>>(bufA, bufB, ea, esrc, eeid, row_ptr, deg, W3e, att3, bias3, bufH, N);
    }

    // ---- attentional pooling + regressor ----
    k_gate<<<N / 64, 256, 0, stream>>>(bufH, G1w, G1b, G2w, G2b, gate, N);
    k_pool<<<64, 256, 0, stream>>>(bufH, gate, batch, pooled, N);
    k_final<<<1, 64, 0, stream>>>(pooled, Wreg, breg, (float*)d_out);
}

// Round 6
// 1707.971 us; speedup vs baseline: 1.1606x; 1.1606x over previous
//
#include <hip/hip_runtime.h>

__global__ void k_fill(unsigned* p, int n, unsigned v) {
    int i = blockIdx.x * blockDim.x + threadIdx.x;
    if (i < n) p[i] = v;
}

// ---------------- CSR build (graph identical across layers; built once) ----------------
__global__ void k_hist(const int* __restrict__ ei, int E, int* __restrict__ deg) {
    int e = blockIdx.x * blockDim.x + threadIdx.x;
    if (e < E) atomicAdd(&deg[ei[E + e]], 1);
}

__global__ void k_scan_blocks(const int* __restrict__ deg, int N,
                              int* __restrict__ excl, int* __restrict__ parts) {
    __shared__ int s[256];
    int t = threadIdx.x, i = blockIdx.x * 256 + t;
    int v = (i < N) ? deg[i] : 0;
    s[t] = v;
    __syncthreads();
    int acc = v;
    for (int off = 1; off < 256; off <<= 1) {
        int add = (t >= off) ? s[t - off] : 0;
        __syncthreads();
        acc += add;
        s[t] = acc;
        __syncthreads();
    }
    if (i < N) excl[i] = acc - v;
    if (t == 255) parts[blockIdx.x] = acc;
}

__global__ void k_scan_parts(int* __restrict__ parts, int nb) {
    __shared__ int s[256];
    int t = threadIdx.x;
    int v = (t < nb) ? parts[t] : 0;
    s[t] = v;
    __syncthreads();
    int acc = v;
    for (int off = 1; off < 256; off <<= 1) {
        int add = (t >= off) ? s[t - off] : 0;
        __syncthreads();
        acc += add;
        s[t] = acc;
        __syncthreads();
    }
    if (t < nb) parts[t] = acc - v;
}

__global__ void k_scan_add(const int* __restrict__ excl, const int* __restrict__ parts,
                           int* __restrict__ row_ptr, int* __restrict__ cursor, int N) {
    int i = blockIdx.x * blockDim.x + threadIdx.x;
    if (i >= N) return;
    int r = excl[i] + parts[i >> 8];
    row_ptr[i] = r;
    cursor[i] = r;
}

__global__ void k_scatter(const int* __restrict__ ei, int E, int* __restrict__ cursor,
                          int* __restrict__ esrc, int* __restrict__ eeid) {
    int e = blockIdx.x * blockDim.x + threadIdx.x;
    if (e >= E) return;
    int d = ei[E + e];
    int j = atomicAdd(&cursor[d], 1);
    esrc[j] = ei[e];
    eeid[j] = e;
}

// fill edst[slot] = dst node (CSR ranges, one thread per node)
__global__ void k_dstfill(const int* __restrict__ row_ptr, const int* __restrict__ deg,
                          int* __restrict__ edst, int N) {
    int n = blockIdx.x * blockDim.x + threadIdx.x;
    if (n >= N) return;
    int s = row_ptr[n], d = deg[n];
    for (int i = 0; i < d; i++) edst[s + i] = n;
}

// ---------------- Dual GEMM: out{l,r} = A @ W{l,r} + b{l,r} ----------------
template <int M, int RW>
__global__ __launch_bounds__(256) void k_gemm2(const float* __restrict__ A,
                                               const float* __restrict__ Wl, const float* __restrict__ bl,
                                               const float* __restrict__ Wr, const float* __restrict__ br,
                                               float* __restrict__ outl, float* __restrict__ outr) {
    constexpr int TX = M / 4;
    __shared__ float sA[32][68];
    __shared__ float sW[32][M];
    const float* W    = blockIdx.y ? Wr : Wl;
    const float* bias = blockIdx.y ? br : bl;
    float* out        = blockIdx.y ? outr : outl;
    int t = threadIdx.x;
    int tx = t % TX, ty = t / TX;
    int r0 = blockIdx.x * 64;
    float acc[RW][4] = {};
    for (int kt = 0; kt < 128; kt += 32) {
        for (int l = t; l < 512; l += 256) {
            int row = l >> 3, kq = (l & 7) << 2;
            float4 a = *(const float4*)&A[(size_t)(r0 + row) * 128 + kt + kq];
            sA[kq + 0][row] = a.x; sA[kq + 1][row] = a.y;
            sA[kq + 2][row] = a.z; sA[kq + 3][row] = a.w;
        }
        for (int l = t; l < 32 * M / 4; l += 256) {
            int kk = (l * 4) / M, cc = (l * 4) % M;
            *(float4*)&sW[kk][cc] = *(const float4*)&W[(size_t)(kt + kk) * M + cc];
        }
        __syncthreads();
#pragma unroll
        for (int k = 0; k < 32; k++) {
            float4 w = *(float4*)&sW[k][tx * 4];
            float ar[RW];
#pragma unroll
            for (int i = 0; i < RW; i += 4) {
                float4 a = *(float4*)&sA[k][ty * RW + i];
                ar[i] = a.x; ar[i + 1] = a.y; ar[i + 2] = a.z; ar[i + 3] = a.w;
            }
#pragma unroll
            for (int i = 0; i < RW; i++) {
                acc[i][0] += ar[i] * w.x; acc[i][1] += ar[i] * w.y;
                acc[i][2] += ar[i] * w.z; acc[i][3] += ar[i] * w.w;
            }
        }
        __syncthreads();
    }
    float4 b = *(const float4*)&bias[tx * 4];
#pragma unroll
    for (int i = 0; i < RW; i++) {
        float4 v;
        v.x = acc[i][0] + b.x; v.y = acc[i][1] + b.y;
        v.z = acc[i][2] + b.z; v.w = acc[i][3] + b.w;
        *(float4*)&out[(size_t)(r0 + ty * RW + i) * M + tx * 4] = v;
    }
}

// ---------------- Edge logit kernel: per CSR slot s, per head h ----------------
// logit[s,h] = sum_c att[h,c] * leaky( xl[src,c] + xr[dst,c] + (ea[eid] @ We)[c] )
// ROWS=32, 256 threads: RW=4 (HC=128) / 2 (HC=64). Round-4's 64-row RW=8 version
// needed VGPR=220 (occupancy 11.5%); round-5's 512-thread cap spilled (758MB scratch
// writes). Halving rows-per-thread keeps acc=16 + epilogue liveness ~32 floats ->
// under the 128-VGPR occupancy step, no cap, no spill. GEMM: transposed-LDS float4
// reads; epilogue gathers xl/xr coalesced float4 and 16-lane shuffle-reduces per head.
template <int HC>
__global__ __launch_bounds__(256) void k_elogit(const float* __restrict__ ea,
                                                const int* __restrict__ eeid,
                                                const int* __restrict__ esrc,
                                                const int* __restrict__ edst,
                                                const float* __restrict__ We,
                                                const float* __restrict__ att,
                                                const float* __restrict__ xl,
                                                const float* __restrict__ xr,
                                                float* __restrict__ logit, int E) {
    constexpr int ROWS = 32;
    constexpr int TX = HC / 4;             // 32 (HC=128) or 16 (HC=64)
    constexpr int RW = ROWS / (256 / TX);  // 4 or 2
    __shared__ float sA[32][ROWS + 4];     // k-major: sA[k][row]
    __shared__ float sW[32][HC];
    int sb = blockIdx.x * ROWS;
    if (sb >= E) return;
    int t = threadIdx.x;
    {   // ROWS*8 = 256 float4 chunks: one per thread
        int row = t >> 3, kq = (t & 7) << 2;
        int s = sb + row;
        int eid = (s < E) ? eeid[s] : 0;
        float4 a = *(const float4*)&ea[(size_t)eid * 32 + kq];
        sA[kq + 0][row] = a.x; sA[kq + 1][row] = a.y;
        sA[kq + 2][row] = a.z; sA[kq + 3][row] = a.w;
    }
    for (int l = t; l < 32 * HC / 4; l += 256) {
        int k = (l * 4) / HC, c = (l * 4) % HC;
        *(float4*)&sW[k][c] = *(const float4*)&We[k * HC + c];
    }
    __syncthreads();
    int tx = t % TX, ty = t / TX;
    float4 attv = *(const float4*)&att[tx * 4];
    float acc[RW][4] = {};
#pragma unroll
    for (int k = 0; k < 32; k++) {
        float4 w = *(float4*)&sW[k][tx * 4];
        float ar[RW];
        if constexpr (RW == 4) {
            float4 a = *(float4*)&sA[k][ty * 4];
            ar[0] = a.x; ar[1] = a.y; ar[2] = a.z; ar[3] = a.w;
        } else {
            float2 a = *(float2*)&sA[k][ty * 2];
            ar[0] = a.x; ar[1] = a.y;
        }
#pragma unroll
        for (int i = 0; i < RW; i++) {
            acc[i][0] = fmaf(ar[i], w.x, acc[i][0]);
            acc[i][1] = fmaf(ar[i], w.y, acc[i][1]);
            acc[i][2] = fmaf(ar[i], w.z, acc[i][2]);
            acc[i][3] = fmaf(ar[i], w.w, acc[i][3]);
        }
    }
#pragma unroll
    for (int i = 0; i < RW; i++) {
        int s = sb + ty * RW + i;
        bool ok = s < E;
        int src = ok ? esrc[s] : 0;
        int dst = ok ? edst[s] : 0;
        float4 xl4 = *(const float4*)&xl[(size_t)src * HC + tx * 4];
        float4 xr4 = *(const float4*)&xr[(size_t)dst * HC + tx * 4];
        float v0 = acc[i][0] + xl4.x + xr4.x; v0 = v0 > 0.f ? v0 : 0.2f * v0;
        float v1 = acc[i][1] + xl4.y + xr4.y; v1 = v1 > 0.f ? v1 : 0.2f * v1;
        float v2 = acc[i][2] + xl4.z + xr4.z; v2 = v2 > 0.f ? v2 : 0.2f * v2;
        float v3 = acc[i][3] + xl4.w + xr4.w; v3 = v3 > 0.f ? v3 : 0.2f * v3;
        float p = fmaf(attv.x, v0, fmaf(attv.y, v1, fmaf(attv.z, v2, attv.w * v3)));
#pragma unroll
        for (int m = 1; m < 16; m <<= 1) p += __shfl_xor(p, m);
        if constexpr (HC == 128) {
            if ((tx & 15) == 0 && ok) logit[2 * (size_t)s + (tx >> 4)] = p;
        } else {
            if (tx == 0 && ok) logit[s] = p;
        }
    }
}

// ---------------- Lean aggregation using precomputed logits ----------------
// Per visit: esrc (4B), logit (broadcast), xl float2 (coalesced 512B/wave), exp, 2 FMA.
// No shuffle butterfly, no We, no ea. Block = 4 waves = 2 nodes x 2 edge-parity waves.
// H==2: lane-half = head. H==1: lane-half = extra edge parity (4 edges in flight/wave-pair).
template <int H, bool RELU>
__global__ __launch_bounds__(256) void k_aggv(const float* __restrict__ xl,
                                              const float* __restrict__ logit,
                                              const int* __restrict__ esrc,
                                              const int* __restrict__ row_ptr, const int* __restrict__ deg,
                                              const float* __restrict__ bias,
                                              float* __restrict__ out, int N) {
    constexpr int HC = H * 64;
    __shared__ float2 sAcc[2][64];
    __shared__ float  sDen[2][64];
    int tid = threadIdx.x, wv = tid >> 6, lane = tid & 63;
    int ns = wv >> 1, eh = wv & 1;
    int n = blockIdx.x * 2 + ns;
    bool alive = n < N;
    int hf = lane >> 5, c2 = lane & 31;
    int col = (H == 2) ? (hf * 64 + 2 * c2) : (2 * c2);
    int start = 0, d = 0;
    if (alive) { start = row_ptr[n]; d = deg[n]; }
    float2 acc = make_float2(0.f, 0.f);
    float den = 0.f;
    const int jstep = (H == 2) ? 2 : 4;
    int jc = (H == 2) ? eh : (2 * eh + hf);

    bool okc = jc < d;
    int sC = start + jc, sN = sC + jstep;
    float lgC = 0.f;
    float2 xlC = make_float2(0.f, 0.f);
    if (okc) {
        lgC = (H == 2) ? logit[2 * (size_t)sC + hf] : logit[sC];
        xlC = *(const float2*)&xl[(size_t)esrc[sC] * HC + col];
    }
    bool okn = (jc + jstep) < d;
    while (okc) {
        float lgN = 0.f;
        float2 xlN = make_float2(0.f, 0.f);
        if (okn) {
            lgN = (H == 2) ? logit[2 * (size_t)sN + hf] : logit[sN];
            xlN = *(const float2*)&xl[(size_t)esrc[sN] * HC + col];
        }
        float ex = __expf(lgC);
        acc.x = fmaf(ex, xlC.x, acc.x);
        acc.y = fmaf(ex, xlC.y, acc.y);
        den += ex;
        jc += jstep; sC = sN; sN += jstep;
        lgC = lgN; xlC = xlN;
        okc = okn; okn = (jc + jstep) < d;
    }

    if constexpr (H == 1) {   // halves hold disjoint edge subsets of same channels
        acc.x += __shfl_xor(acc.x, 32);
        acc.y += __shfl_xor(acc.y, 32);
        den   += __shfl_xor(den, 32);
    }
    if (eh == 1) { sAcc[ns][lane] = acc; sDen[ns][lane] = den; }
    __syncthreads();
    if (eh == 0 && alive) {
        float2 a2 = sAcc[ns][lane];
        float dsum = den + sDen[ns][lane] + 1e-16f;
        float2 bv = *(const float2*)&bias[col];
        float o0 = (acc.x + a2.x) / dsum + bv.x;
        float o1 = (acc.y + a2.y) / dsum + bv.y;
        if (RELU) { o0 = fmaxf(o0, 0.f); o1 = fmaxf(o1, 0.f); }
        if (H == 2 || hf == 0)
            *(float2*)&out[(size_t)n * HC + col] = make_float2(o0, o1);
    }
}

// ---------------- Fallback agg (round-0 structure) — tiny-workspace path ----------------
template <int H, bool RELU>
__global__ __launch_bounds__(256) void k_agg_fb(const float* __restrict__ xl, const float* __restrict__ xr,
                                                const float* __restrict__ ea,
                                                const int* __restrict__ esrc, const int* __restrict__ eeid,
                                                const int* __restrict__ row_ptr, const int* __restrict__ deg,
                                                const float* __restrict__ We, const float* __restrict__ att,
                                                const float* __restrict__ bias, float* __restrict__ out, int N) {
    constexpr int HC = H * 64;
    int tid = threadIdx.x, wv = tid >> 6, lane = tid & 63;
    float rWe0[32], rWe1[H == 2 ? 32 : 1];
#pragma unroll
    for (int k = 0; k < 32; k++) rWe0[k] = We[k * HC + lane];
    if constexpr (H == 2) {
#pragma unroll
        for (int k = 0; k < 32; k++) rWe1[k] = We[k * HC + 64 + lane];
    }
    float att0 = att[lane], b0 = bias[lane];
    float att1 = 0.f, b1 = 0.f;
    if constexpr (H == 2) { att1 = att[64 + lane]; b1 = bias[64 + lane]; }
    int n = blockIdx.x * 4 + wv;
    if (n >= N) return;
    int start = row_ptr[n], d = deg[n];
    float xr0 = xr[(size_t)n * HC + lane];
    float xr1 = (H == 2) ? xr[(size_t)n * HC + 64 + lane] : 0.f;
    float acc0 = 0.f, acc1 = 0.f, den0 = 0.f, den1 = 0.f;
    for (int j = 0; j < d; j++) {
        int src = esrc[start + j], eid = eeid[start + j];
        const float4* eap = (const float4*)(ea + (size_t)eid * 32);
        const float* xls = xl + (size_t)src * HC;
        float xl0 = xls[lane];
        float xl1 = (H == 2) ? xls[64 + lane] : 0.f;
        float ee0 = 0.f, ee1 = 0.f;
#pragma unroll
        for (int kq = 0; kq < 8; kq++) {
            float4 v = eap[kq];
            ee0 = fmaf(v.x, rWe0[kq * 4 + 0], ee0);
            ee0 = fmaf(v.y, rWe0[kq * 4 + 1], ee0);
            ee0 = fmaf(v.z, rWe0[kq * 4 + 2], ee0);
            ee0 = fmaf(v.w, rWe0[kq * 4 + 3], ee0);
            if constexpr (H == 2) {
                ee1 = fmaf(v.x, rWe1[kq * 4 + 0], ee1);
                ee1 = fmaf(v.y, rWe1[kq * 4 + 1], ee1);
                ee1 = fmaf(v.z, rWe1[kq * 4 + 2], ee1);
                ee1 = fmaf(v.w, rWe1[kq * 4 + 3], ee1);
            }
        }
        float v0 = xl0 + xr0 + ee0;
        v0 = v0 > 0.f ? v0 : 0.2f * v0;
        float p0 = att0 * v0, p1 = 0.f;
        if constexpr (H == 2) {
            float v1 = xl1 + xr1 + ee1;
            v1 = v1 > 0.f ? v1 : 0.2f * v1;
            p1 = att1 * v1;
        }
#pragma unroll
        for (int m = 32; m; m >>= 1) {
            p0 += __shfl_xor(p0, m);
            if constexpr (H == 2) p1 += __shfl_xor(p1, m);
        }
        float ex0 = __expf(p0);
        acc0 = fmaf(ex0, xl0, acc0);
        den0 += ex0;
        if constexpr (H == 2) {
            float ex1 = __expf(p1);
            acc1 = fmaf(ex1, xl1, acc1);
            den1 += ex1;
        }
    }
    float o0 = acc0 / (den0 + 1e-16f) + b0;
    if (RELU) o0 = o0 > 0.f ? o0 : 0.f;
    out[(size_t)n * HC + lane] = o0;
    if constexpr (H == 2) {
        float o1 = acc1 / (den1 + 1e-16f) + b1;
        if (RELU) o1 = o1 > 0.f ? o1 : 0.f;
        out[(size_t)n * HC + 64 + lane] = o1;
    }
}

// ---------------- gate MLP ----------------
__global__ __launch_bounds__(256) void k_gate(const float* __restrict__ h, const float* __restrict__ G1w,
                                              const float* __restrict__ G1b, const float* __restrict__ G2w,
                                              const float* __restrict__ G2b,
                                              float* __restrict__ gate, int N) {
    __shared__ float sH[64][64];
    __shared__ float part[64][2];
    int t = threadIdx.x;
    int n0 = blockIdx.x * 64;
    for (int l = t; l < 1024; l += 256) {
        float4 v = ((const float4*)(h + (size_t)n0 * 64))[l];
        int n = l >> 4, kq = (l & 15) << 2;
        *(float4*)&sH[n][kq] = v;
    }
    int c = t & 127, half = t >> 7;
    float rW[64];
#pragma unroll
    for (int k = 0; k < 64; k++) rW[k] = G1w[k * 128 + c];
    float g1b = G1b[c], g2w = G2w[c];
    __syncthreads();
    for (int nn = 0; nn < 32; nn++) {
        int n = half * 32 + nn;
        float acc = g1b;
#pragma unroll
        for (int k = 0; k < 64; k += 4) {
            float4 hv = *(const float4*)&sH[n][k];
            acc = fmaf(hv.x, rW[k], acc);
            acc = fmaf(hv.y, rW[k + 1], acc);
            acc = fmaf(hv.z, rW[k + 2], acc);
            acc = fmaf(hv.w, rW[k + 3], acc);
        }
        acc = acc > 0.f ? acc : 0.f;
        float p = acc * g2w;
#pragma unroll
        for (int m = 32; m; m >>= 1) p += __shfl_xor(p, m);
        if ((t & 63) == 0) part[n][(t >> 6) & 1] = p;
    }
    __syncthreads();
    if (t < 64) gate[n0 + t] = __expf(part[t][0] + part[t][1] + G2b[0]);
}

// ---------------- pooling ----------------
__global__ __launch_bounds__(256) void k_pool(const float* __restrict__ h, const float* __restrict__ gate,
                                              const int* __restrict__ batch,
                                              float* __restrict__ pooled, int N) {
    int g = blockIdx.x;
    int lo = 0, hi = N;
    while (lo < hi) { int mid = (lo + hi) >> 1; if (batch[mid] < g) lo = mid + 1; else hi = mid; }
    int start = lo;
    lo = 0; hi = N;
    while (lo < hi) { int mid = (lo + hi) >> 1; if (batch[mid] < g + 1) lo = mid + 1; else hi = mid; }
    int end = lo;
    int t = threadIdx.x, wv = t >> 6, lane = t & 63;
    float acc = 0.f, den = 0.f;
    for (int n = start + wv; n < end; n += 4) {
        float gv = gate[n];
        acc = fmaf(gv, h[(size_t)n * 64 + lane], acc);
        den += gv;
    }
    __shared__ float sacc[4][64];
    __shared__ float sden[4];
    sacc[wv][lane] = acc;
    if (lane == 0) sden[wv] = den;
    __syncthreads();
    if (wv == 0) {
        float a = sacc[0][lane] + sacc[1][lane] + sacc[2][lane] + sacc[3][lane];
        float d = sden[0] + sden[1] + sden[2] + sden[3] + 1e-16f;
        pooled[g * 64 + lane] = a / d;
    }
}

__global__ void k_final(const float* __restrict__ pooled, const float* __restrict__ Wreg,
                        const float* __restrict__ breg, float* __restrict__ out) {
    int g = threadIdx.x;
    float acc = breg[0];
    for (int c = 0; c < 64; c++) acc += pooled[g * 64 + c] * Wreg[c];
    out[g] = acc;
}

extern "C" void kernel_launch(void* const* d_in, const int* in_sizes, int n_in,
                              void* d_out, int out_size, void* d_ws, size_t ws_size,
                              hipStream_t stream) {
    const float* x  = (const float*)d_in[0];
    const float* ea = (const float*)d_in[1];
    const int* ei    = (const int*)d_in[2];
    const int* batch = (const int*)d_in[3];
    auto ff = [&](int i) { return (const float*)d_in[i]; };
    const float *W1l = ff(4), *b1l = ff(5), *W1r = ff(6), *b1r = ff(7), *W1e = ff(8),
                *att1 = ff(9), *bias1 = ff(10);
    const float *W2l = ff(11), *b2l = ff(12), *W2r = ff(13), *b2r = ff(14), *W2e = ff(15),
                *att2 = ff(16), *bias2 = ff(17);
    const float *W3l = ff(18), *b3l = ff(19), *W3r = ff(20), *b3r = ff(21), *W3e = ff(22),
                *att3 = ff(23), *bias3 = ff(24);
    const float *G1w = ff(25), *G1b = ff(26), *G2w = ff(27), *G2b = ff(28), *Wreg = ff(29),
                *breg = ff(30);

    const int N = in_sizes[0] / 128;  // 40000
    const int E = in_sizes[2] / 2;    // 640000

    char* ws = (char*)d_ws;
    float*  bufA    = (float*)(ws);              // [N,128]
    float*  bufB    = (float*)(ws + 20480000);   // [N,128]
    float*  bufH    = (float*)(ws + 40960000);   // [N,128]
    int*    esrc    = (int*)(ws + 61440000);     // [E]
    int*    eeid    = (int*)(ws + 64000000);     // [E]
    int*    row_ptr = (int*)(ws + 66560000);     // [N]
    int*    deg     = (int*)(ws + 66720000);     // [N]
    int*    cursor  = (int*)(ws + 66880000);     // [N]
    int*    excl    = (int*)(ws + 67040000);     // [N]
    int*    parts   = (int*)(ws + 67200000);     // [<=256]
    float*  gate    = (float*)(ws + 67204096);   // [N]
    float*  pooled  = (float*)(ws + 67364096);   // [64,64]
    int*    edst    = (int*)(ws + 67380480);     // [E]
    float*  logit   = (float*)(ws + 69940480);   // [E,2]
    const bool newpath = ws_size >= (size_t)69940480 + (size_t)E * 2 * 4;

    auto cdiv = [](int a, int b) { return (a + b - 1) / b; };
    const int NB = cdiv(N, 256);
    const dim3 gemmG(N / 64, 2);
    const int ELB = cdiv(E, 32);
    const int AGB = cdiv(N, 2);

    // ---- CSR build (once; graph shared by all 3 layers) ----
    k_fill<<<NB, 256, 0, stream>>>((unsigned*)deg, N, 0u);
    k_hist<<<cdiv(E, 256), 256, 0, stream>>>(ei, E, deg);
    k_scan_blocks<<<NB, 256, 0, stream>>>(deg, N, excl, parts);
    k_scan_parts<<<1, 256, 0, stream>>>(parts, NB);
    k_scan_add<<<NB, 256, 0, stream>>>(excl, parts, row_ptr, cursor, N);
    k_scatter<<<cdiv(E, 256), 256, 0, stream>>>(ei, E, cursor, esrc, eeid);

    if (newpath) {
        k_dstfill<<<NB, 256, 0, stream>>>(row_ptr, deg, edst, N);
        // ---- layer 1 ----
        k_gemm2<128, 8><<<gemmG, 256, 0, stream>>>(x, W1l, b1l, W1r, b1r, bufA, bufB);
        k_elogit<128><<<ELB, 256, 0, stream>>>(ea, eeid, esrc, edst, W1e, att1, bufA, bufB, logit, E);
        k_aggv<2, true><<<AGB, 256, 0, stream>>>(bufA, logit, esrc, row_ptr, deg, bias1, bufH, N);
        // ---- layer 2 ----
        k_gemm2<128, 8><<<gemmG, 256, 0, stream>>>(bufH, W2l, b2l, W2r, b2r, bufA, bufB);
        k_elogit<128><<<ELB, 256, 0, stream>>>(ea, eeid, esrc, edst, W2e, att2, bufA, bufB, logit, E);
        k_aggv<2, true><<<AGB, 256, 0, stream>>>(bufA, logit, esrc, row_ptr, deg, bias2, bufH, N);
        // ---- layer 3 ----
        k_gemm2<64, 4><<<gemmG, 256, 0, stream>>>(bufH, W3l, b3l, W3r, b3r, bufA, bufB);
        k_elogit<64><<<ELB, 256, 0, stream>>>(ea, eeid, esrc, edst, W3e, att3, bufA, bufB, logit, E);
        k_aggv<1, false><<<AGB, 256, 0, stream>>>(bufA, logit, esrc, row_ptr, deg, bias3, bufH, N);
    } else {
        const int AGGB = cdiv(N, 4);
        k_gemm2<128, 8><<<gemmG, 256, 0, stream>>>(x, W1l, b1l, W1r, b1r, bufA, bufB);
        k_agg_fb<2, true><<<AGGB, 256, 0, stream>>>(bufA, bufB, ea, esrc, eeid, row_ptr, deg, W1e, att1, bias1, bufH, N);
        k_gemm2<128, 8><<<gemmG, 256, 0, stream>>>(bufH, W2l, b2l, W2r, b2r, bufA, bufB);
        k_agg_fb<2, true><<<AGGB, 256, 0, stream>>>(bufA, bufB, ea, esrc, eeid, row_ptr, deg, W2e, att2, bias2, bufH, N);
        k_gemm2<64, 4><<<gemmG, 256, 0, stream>>>(bufH, W3l, b3l, W3r, b3r, bufA, bufB);
        k_agg_fb<1, false><<<AGGB, 256, 0, stream>>>(bufA, bufB, ea, esrc, eeid, row_ptr, deg, W3e, att3, bias3, bufH, N);
    }

    // ---- attentional pooling + regressor ----
    k_gate<<<N / 64, 256, 0, stream>>>(bufH, G1w, G1b, G2w, G2b, gate, N);
    k_pool<<<64, 256, 0, stream>>>(bufH, gate, batch, pooled, N);
    k_final<<<1, 64, 0, stream>>>(pooled, Wreg, breg, (float*)d_out);
}

// Round 7
// 1378.494 us; speedup vs baseline: 1.4380x; 1.2390x over previous
//
#include <hip/hip_runtime.h>

__global__ void k_fill(unsigned* p, int n, unsigned v) {
    int i = blockIdx.x * blockDim.x + threadIdx.x;
    if (i < n) p[i] = v;
}

// ---------------- CSR build (graph identical across layers; built once) ----------------
__global__ void k_hist(const int* __restrict__ ei, int E, int* __restrict__ deg) {
    int e = blockIdx.x * blockDim.x + threadIdx.x;
    if (e < E) atomicAdd(&deg[ei[E + e]], 1);
}

__global__ void k_scan_blocks(const int* __restrict__ deg, int N,
                              int* __restrict__ excl, int* __restrict__ parts) {
    __shared__ int s[256];
    int t = threadIdx.x, i = blockIdx.x * 256 + t;
    int v = (i < N) ? deg[i] : 0;
    s[t] = v;
    __syncthreads();
    int acc = v;
    for (int off = 1; off < 256; off <<= 1) {
        int add = (t >= off) ? s[t - off] : 0;
        __syncthreads();
        acc += add;
        s[t] = acc;
        __syncthreads();
    }
    if (i < N) excl[i] = acc - v;
    if (t == 255) parts[blockIdx.x] = acc;
}

__global__ void k_scan_parts(int* __restrict__ parts, int nb) {
    __shared__ int s[256];
    int t = threadIdx.x;
    int v = (t < nb) ? parts[t] : 0;
    s[t] = v;
    __syncthreads();
    int acc = v;
    for (int off = 1; off < 256; off <<= 1) {
        int add = (t >= off) ? s[t - off] : 0;
        __syncthreads();
        acc += add;
        s[t] = acc;
        __syncthreads();
    }
    if (t < nb) parts[t] = acc - v;
}

__global__ void k_scan_add(const int* __restrict__ excl, const int* __restrict__ parts,
                           int* __restrict__ row_ptr, int* __restrict__ cursor, int N) {
    int i = blockIdx.x * blockDim.x + threadIdx.x;
    if (i >= N) return;
    int r = excl[i] + parts[i >> 8];
    row_ptr[i] = r;
    cursor[i] = r;
}

__global__ void k_scatter(const int* __restrict__ ei, int E, int* __restrict__ cursor,
                          int2* __restrict__ elist) {
    int e = blockIdx.x * blockDim.x + threadIdx.x;
    if (e >= E) return;
    int d = ei[E + e];
    int j = atomicAdd(&cursor[d], 1);
    elist[j] = make_int2(ei[e], e);
}

// ---------------- Dual GEMM: out{l,r} = A @ W{l,r} + b{l,r} ----------------
template <int M, int RW>
__global__ __launch_bounds__(256) void k_gemm2(const float* __restrict__ A,
                                               const float* __restrict__ Wl, const float* __restrict__ bl,
                                               const float* __restrict__ Wr, const float* __restrict__ br,
                                               float* __restrict__ outl, float* __restrict__ outr) {
    constexpr int TX = M / 4;
    __shared__ float sA[32][68];
    __shared__ float sW[32][M];
    const float* W    = blockIdx.y ? Wr : Wl;
    const float* bias = blockIdx.y ? br : bl;
    float* out        = blockIdx.y ? outr : outl;
    int t = threadIdx.x;
    int tx = t % TX, ty = t / TX;
    int r0 = blockIdx.x * 64;
    float acc[RW][4] = {};
    for (int kt = 0; kt < 128; kt += 32) {
        for (int l = t; l < 512; l += 256) {
            int row = l >> 3, kq = (l & 7) << 2;
            float4 a = *(const float4*)&A[(size_t)(r0 + row) * 128 + kt + kq];
            sA[kq + 0][row] = a.x; sA[kq + 1][row] = a.y;
            sA[kq + 2][row] = a.z; sA[kq + 3][row] = a.w;
        }
        for (int l = t; l < 32 * M / 4; l += 256) {
            int kk = (l * 4) / M, cc = (l * 4) % M;
            *(float4*)&sW[kk][cc] = *(const float4*)&W[(size_t)(kt + kk) * M + cc];
        }
        __syncthreads();
#pragma unroll
        for (int k = 0; k < 32; k++) {
            float4 w = *(float4*)&sW[k][tx * 4];
            float ar[RW];
#pragma unroll
            for (int i = 0; i < RW; i += 4) {
                float4 a = *(float4*)&sA[k][ty * RW + i];
                ar[i] = a.x; ar[i + 1] = a.y; ar[i + 2] = a.z; ar[i + 3] = a.w;
            }
#pragma unroll
            for (int i = 0; i < RW; i++) {
                acc[i][0] += ar[i] * w.x; acc[i][1] += ar[i] * w.y;
                acc[i][2] += ar[i] * w.z; acc[i][3] += ar[i] * w.w;
            }
        }
        __syncthreads();
    }
    float4 b = *(const float4*)&bias[tx * 4];
#pragma unroll
    for (int i = 0; i < RW; i++) {
        float4 v;
        v.x = acc[i][0] + b.x; v.y = acc[i][1] + b.y;
        v.z = acc[i][2] + b.z; v.w = acc[i][3] + b.w;
        *(float4*)&out[(size_t)(r0 + ty * RW + i) * M + tx * 4] = v;
    }
}

// ---------------- Edge transform GEMM: ee[slot] = ea[elist[slot].y] @ We ----------------
// Streams CSR slots [s0, s1) of chunk [n0, n1); writes ee chunk-relative (slot - s0).
// ROWS=32 retile (round 7): RW=4 (HC=128) / 2 (HC=64), acc=16/8 floats, one staging
// float4 per thread. Round-3's 64-row version hit VGPR=140 -> 10.9% occupancy,
// latency-bound at ~2.5 TB/s effective. No node-row gathers here by design (the
// gather-in-GEMM-epilogue structure measured 3x slower in rounds 4-6).
template <int HC>
__global__ __launch_bounds__(256) void k_edge_gemm(const float* __restrict__ ea,
                                                   const int2* __restrict__ elist,
                                                   const int* __restrict__ row_ptr,
                                                   const float* __restrict__ We,
                                                   float* __restrict__ ee,
                                                   int n0, int n1, int Ntot, int E) {
    constexpr int ROWS = 32;
    constexpr int TX = HC / 4;             // 32 (HC=128) or 16 (HC=64)
    constexpr int RW = ROWS * TX / 256;    // 4 or 2
    int s0 = row_ptr[n0];
    int s1 = (n1 >= Ntot) ? E : row_ptr[n1];
    int sb = s0 + blockIdx.x * ROWS;
    if (sb >= s1) return;
    __shared__ float sA[ROWS][33];
    __shared__ float sW[32][HC];
    int t = threadIdx.x;
    {   // 32 rows x 8 float4 = 256 loads: one per thread
        int row = t >> 3, q = t & 7;
        int s = sb + row;
        int eid = (s < s1) ? elist[s].y : 0;
        float4 a = *(const float4*)&ea[(size_t)eid * 32 + q * 4];
        *(float4*)&sA[row][q * 4] = a;
    }
    for (int l = t; l < 32 * HC / 4; l += 256) {
        int k = (l * 4) / HC, c = (l * 4) % HC;
        *(float4*)&sW[k][c] = *(const float4*)&We[k * HC + c];
    }
    __syncthreads();
    int tx = t % TX, ty = t / TX;
    float acc[RW][4] = {};
#pragma unroll
    for (int k = 0; k < 32; k++) {
        float4 w = *(float4*)&sW[k][tx * 4];
#pragma unroll
        for (int i = 0; i < RW; i++) {
            float a = sA[ty * RW + i][k];
            acc[i][0] = fmaf(a, w.x, acc[i][0]);
            acc[i][1] = fmaf(a, w.y, acc[i][1]);
            acc[i][2] = fmaf(a, w.z, acc[i][2]);
            acc[i][3] = fmaf(a, w.w, acc[i][3]);
        }
    }
#pragma unroll
    for (int i = 0; i < RW; i++) {
        int s = sb + ty * RW + i;
        if (s < s1)
            *(float4*)&ee[(size_t)(s - s0) * HC + tx * 4] =
                make_float4(acc[i][0], acc[i][1], acc[i][2], acc[i][3]);
    }
}

// ---------------- Lean fused GATv2 aggregation (uses precomputed ee) ----------------
// 2 channels per lane. H==2: lane-half = head (both heads of an edge in one visit).
// H==1: lane-half = edge parity within the wave (2 edges per visit).
// Block = 4 waves = 2 nodes x 2 parity waves; parity halves merge via LDS.
// 2-deep pipeline: elist prefetched 2 edges ahead (linear addr), ee/xl 1 ahead,
// so the elist->xl dependent gather is off the per-iteration critical path.
template <int H, bool RELU>
__global__ __launch_bounds__(256) void k_aggv(const float* __restrict__ xl, const float* __restrict__ xr,
                                              const float* __restrict__ ee,
                                              const int2* __restrict__ elist,
                                              const int* __restrict__ row_ptr, const int* __restrict__ deg,
                                              const float* __restrict__ att, const float* __restrict__ bias,
                                              float* __restrict__ out, int n0, int n1) {
    constexpr int HC = H * 64;
    __shared__ float2 sAcc[2][64];
    __shared__ float  sDen[2][64];
    int tid = threadIdx.x, wv = tid >> 6, lane = tid & 63;
    int ns = wv >> 1, eh = wv & 1;
    int n = n0 + blockIdx.x * 2 + ns;
    bool alive = n < n1;
    int hf = lane >> 5, c2 = lane & 31;
    int col = (H == 2) ? (hf * 64 + 2 * c2) : (2 * c2);
    float2 attv = *(const float2*)&att[col];
    int s0 = row_ptr[n0];
    float2 xrv = make_float2(0.f, 0.f);
    int start = 0, d = 0;
    if (alive) {
        xrv = *(const float2*)&xr[(size_t)n * HC + col];
        start = row_ptr[n];
        d = deg[n];
    }
    float2 acc = make_float2(0.f, 0.f);
    float den = 0.f;

    const int jstep = (H == 2) ? 2 : 4;
    int jc = (H == 2) ? eh : (2 * eh + hf);
    bool okc = jc < d;
    int sC = start + jc;
    int sN = sC + jstep;
    int spx = okc ? elist[sC].x : 0;
    float2 eeC = okc ? *(const float2*)&ee[(size_t)(sC - s0) * HC + col] : make_float2(0.f, 0.f);
    float2 xlC = okc ? *(const float2*)&xl[(size_t)spx * HC + col] : make_float2(0.f, 0.f);
    bool okn = (jc + jstep) < d;
    int spxN = okn ? elist[sN].x : 0;

    while (okc) {
        bool okn2 = (jc + 2 * jstep) < d;
        int sN2 = sN + jstep;
        int spxN2 = okn2 ? elist[sN2].x : 0;
        float2 eeN = okn ? *(const float2*)&ee[(size_t)(sN - s0) * HC + col] : make_float2(0.f, 0.f);
        float2 xlN = okn ? *(const float2*)&xl[(size_t)spxN * HC + col] : make_float2(0.f, 0.f);

        float v0 = xlC.x + xrv.x + eeC.x;
        float v1 = xlC.y + xrv.y + eeC.y;
        v0 = v0 > 0.f ? v0 : 0.2f * v0;
        v1 = v1 > 0.f ? v1 : 0.2f * v1;
        float p = fmaf(attv.x, v0, attv.y * v1);
#pragma unroll
        for (int m = 16; m; m >>= 1) p += __shfl_xor(p, m);
        float ex = __expf(p);
        acc.x = fmaf(ex, xlC.x, acc.x);
        acc.y = fmaf(ex, xlC.y, acc.y);
        den += ex;

        jc += jstep; sC = sN; sN = sN2;
        xlC = xlN; eeC = eeN; spxN = spxN2;
        okc = okn; okn = okn2;
    }

    if constexpr (H == 1) {   // halves hold disjoint edge subsets of same channels
        acc.x += __shfl_xor(acc.x, 32);
        acc.y += __shfl_xor(acc.y, 32);
        den   += __shfl_xor(den, 32);
    }
    if (eh == 1) { sAcc[ns][lane] = acc; sDen[ns][lane] = den; }
    __syncthreads();
    if (eh == 0 && alive) {
        float2 a = sAcc[ns][lane];
        float dd = sDen[ns][lane];
        float dsum = den + dd + 1e-16f;
        float2 bv = *(const float2*)&bias[col];
        float o0 = (acc.x + a.x) / dsum + bv.x;
        float o1 = (acc.y + a.y) / dsum + bv.y;
        if (RELU) { o0 = fmaxf(o0, 0.f); o1 = fmaxf(o1, 0.f); }
        if (H == 2 || hf == 0)
            *(float2*)&out[(size_t)n * HC + col] = make_float2(o0, o1);
    }
}

// ---------------- Fallback agg (round-0 structure, unsorted ea) — tiny-workspace path ----
template <int H, bool RELU>
__global__ __launch_bounds__(256) void k_agg_fb(const float* __restrict__ xl, const float* __restrict__ xr,
                                                const float* __restrict__ ea,
                                                const int2* __restrict__ elist,
                                                const int* __restrict__ row_ptr, const int* __restrict__ deg,
                                                const float* __restrict__ We, const float* __restrict__ att,
                                                const float* __restrict__ bias, float* __restrict__ out, int N) {
    constexpr int HC = H * 64;
    int tid = threadIdx.x, wv = tid >> 6, lane = tid & 63;
    float rWe0[32], rWe1[H == 2 ? 32 : 1];
#pragma unroll
    for (int k = 0; k < 32; k++) rWe0[k] = We[k * HC + lane];
    if constexpr (H == 2) {
#pragma unroll
        for (int k = 0; k < 32; k++) rWe1[k] = We[k * HC + 64 + lane];
    }
    float att0 = att[lane], b0 = bias[lane];
    float att1 = 0.f, b1 = 0.f;
    if constexpr (H == 2) { att1 = att[64 + lane]; b1 = bias[64 + lane]; }
    int n = blockIdx.x * 4 + wv;
    if (n >= N) return;
    int start = row_ptr[n], d = deg[n];
    float xr0 = xr[(size_t)n * HC + lane];
    float xr1 = (H == 2) ? xr[(size_t)n * HC + 64 + lane] : 0.f;
    float acc0 = 0.f, acc1 = 0.f, den0 = 0.f, den1 = 0.f;
    for (int j = 0; j < d; j++) {
        int2 sp = elist[start + j];
        const float4* eap = (const float4*)(ea + (size_t)sp.y * 32);
        const float* xls = xl + (size_t)sp.x * HC;
        float xl0 = xls[lane];
        float xl1 = (H == 2) ? xls[64 + lane] : 0.f;
        float ee0 = 0.f, ee1 = 0.f;
#pragma unroll
        for (int kq = 0; kq < 8; kq++) {
            float4 v = eap[kq];
            ee0 = fmaf(v.x, rWe0[kq * 4 + 0], ee0);
            ee0 = fmaf(v.y, rWe0[kq * 4 + 1], ee0);
            ee0 = fmaf(v.z, rWe0[kq * 4 + 2], ee0);
            ee0 = fmaf(v.w, rWe0[kq * 4 + 3], ee0);
            if constexpr (H == 2) {
                ee1 = fmaf(v.x, rWe1[kq * 4 + 0], ee1);
                ee1 = fmaf(v.y, rWe1[kq * 4 + 1], ee1);
                ee1 = fmaf(v.z, rWe1[kq * 4 + 2], ee1);
                ee1 = fmaf(v.w, rWe1[kq * 4 + 3], ee1);
            }
        }
        float v0 = xl0 + xr0 + ee0;
        v0 = v0 > 0.f ? v0 : 0.2f * v0;
        float p0 = att0 * v0, p1 = 0.f;
        if constexpr (H == 2) {
            float v1 = xl1 + xr1 + ee1;
            v1 = v1 > 0.f ? v1 : 0.2f * v1;
            p1 = att1 * v1;
        }
#pragma unroll
        for (int m = 32; m; m >>= 1) {
            p0 += __shfl_xor(p0, m);
            if constexpr (H == 2) p1 += __shfl_xor(p1, m);
        }
        float ex0 = __expf(p0);
        acc0 = fmaf(ex0, xl0, acc0);
        den0 += ex0;
        if constexpr (H == 2) {
            float ex1 = __expf(p1);
            acc1 = fmaf(ex1, xl1, acc1);
            den1 += ex1;
        }
    }
    float o0 = acc0 / (den0 + 1e-16f) + b0;
    if (RELU) o0 = o0 > 0.f ? o0 : 0.f;
    out[(size_t)n * HC + lane] = o0;
    if constexpr (H == 2) {
        float o1 = acc1 / (den1 + 1e-16f) + b1;
        if (RELU) o1 = o1 > 0.f ? o1 : 0.f;
        out[(size_t)n * HC + 64 + lane] = o1;
    }
}

// ---------------- gate MLP ----------------
__global__ __launch_bounds__(256) void k_gate(const float* __restrict__ h, const float* __restrict__ G1w,
                                              const float* __restrict__ G1b, const float* __restrict__ G2w,
                                              const float* __restrict__ G2b,
                                              float* __restrict__ gate, int N) {
    __shared__ float sH[64][64];
    __shared__ float part[64][2];
    int t = threadIdx.x;
    int n0 = blockIdx.x * 64;
    for (int l = t; l < 1024; l += 256) {
        float4 v = ((const float4*)(h + (size_t)n0 * 64))[l];
        int n = l >> 4, kq = (l & 15) << 2;
        *(float4*)&sH[n][kq] = v;
    }
    int c = t & 127, half = t >> 7;
    float rW[64];
#pragma unroll
    for (int k = 0; k < 64; k++) rW[k] = G1w[k * 128 + c];
    float g1b = G1b[c], g2w = G2w[c];
    __syncthreads();
    for (int nn = 0; nn < 32; nn++) {
        int n = half * 32 + nn;
        float acc = g1b;
#pragma unroll
        for (int k = 0; k < 64; k += 4) {
            float4 hv = *(const float4*)&sH[n][k];
            acc = fmaf(hv.x, rW[k], acc);
            acc = fmaf(hv.y, rW[k + 1], acc);
            acc = fmaf(hv.z, rW[k + 2], acc);
            acc = fmaf(hv.w, rW[k + 3], acc);
        }
        acc = acc > 0.f ? acc : 0.f;
        float p = acc * g2w;
#pragma unroll
        for (int m = 32; m; m >>= 1) p += __shfl_xor(p, m);
        if ((t & 63) == 0) part[n][(t >> 6) & 1] = p;
    }
    __syncthreads();
    if (t < 64) gate[n0 + t] = __expf(part[t][0] + part[t][1] + G2b[0]);
}

// ---------------- pooling ----------------
__global__ __launch_bounds__(256) void k_pool(const float* __restrict__ h, const float* __restrict__ gate,
                                              const int* __restrict__ batch,
                                              float* __restrict__ pooled, int N) {
    int g = blockIdx.x;
    int lo = 0, hi = N;
    while (lo < hi) { int mid = (lo + hi) >> 1; if (batch[mid] < g) lo = mid + 1; else hi = mid; }
    int start = lo;
    lo = 0; hi = N;
    while (lo < hi) { int mid = (lo + hi) >> 1; if (batch[mid] < g + 1) lo = mid + 1; else hi = mid; }
    int end = lo;
    int t = threadIdx.x, wv = t >> 6, lane = t & 63;
    float acc = 0.f, den = 0.f;
    for (int n = start + wv; n < end; n += 4) {
        float gv = gate[n];
        acc = fmaf(gv, h[(size_t)n * 64 + lane], acc);
        den += gv;
    }
    __shared__ float sacc[4][64];
    __shared__ float sden[4];
    sacc[wv][lane] = acc;
    if (lane == 0) sden[wv] = den;
    __syncthreads();
    if (wv == 0) {
        float a = sacc[0][lane] + sacc[1][lane] + sacc[2][lane] + sacc[3][lane];
        float d = sden[0] + sden[1] + sden[2] + sden[3] + 1e-16f;
        pooled[g * 64 + lane] = a / d;
    }
}

__global__ void k_final(const float* __restrict__ pooled, const float* __restrict__ Wreg,
                        const float* __restrict__ breg, float* __restrict__ out) {
    int g = threadIdx.x;
    float acc = breg[0];
    for (int c = 0; c < 64; c++) acc += pooled[g * 64 + c] * Wreg[c];
    out[g] = acc;
}

// ---------------- host-side per-layer chunked launch ----------------
template <int H, bool RELU>
static void launch_layer_agg(const float* ea, const int2* elist, const int* row_ptr, const int* deg,
                             const float* We, const float* att, const float* bias,
                             const float* xl, const float* xr, float* outb, float* eebuf,
                             size_t avail, int N, int E, hipStream_t stream) {
    constexpr int HC = H * 64;
    size_t need = (size_t)E * HC * 4;
    int K = (avail >= need) ? 1 : (int)((need * 21 / 20 + avail - 1) / avail);
    size_t cap_slots = (K == 1) ? (size_t)E : avail / ((size_t)HC * 4);
    size_t cover = cap_slots < (size_t)E ? cap_slots : (size_t)E;
    int gb = (int)((cover + 31) / 32);
    for (int c = 0; c < K; c++) {
        int n0 = (int)((long long)N * c / K);
        int n1 = (int)((long long)N * (c + 1) / K);
        k_edge_gemm<HC><<<gb, 256, 0, stream>>>(ea, elist, row_ptr, We, eebuf, n0, n1, N, E);
        int nb = (n1 - n0 + 1) / 2;
        k_aggv<H, RELU><<<nb, 256, 0, stream>>>(xl, xr, eebuf, elist, row_ptr, deg, att, bias, outb, n0, n1);
    }
}

extern "C" void kernel_launch(void* const* d_in, const int* in_sizes, int n_in,
                              void* d_out, int out_size, void* d_ws, size_t ws_size,
                              hipStream_t stream) {
    const float* x  = (const float*)d_in[0];
    const float* ea = (const float*)d_in[1];
    const int* ei    = (const int*)d_in[2];
    const int* batch = (const int*)d_in[3];
    auto ff = [&](int i) { return (const float*)d_in[i]; };
    const float *W1l = ff(4), *b1l = ff(5), *W1r = ff(6), *b1r = ff(7), *W1e = ff(8),
                *att1 = ff(9), *bias1 = ff(10);
    const float *W2l = ff(11), *b2l = ff(12), *W2r = ff(13), *b2r = ff(14), *W2e = ff(15),
                *att2 = ff(16), *bias2 = ff(17);
    const float *W3l = ff(18), *b3l = ff(19), *W3r = ff(20), *b3r = ff(21), *W3e = ff(22),
                *att3 = ff(23), *bias3 = ff(24);
    const float *G1w = ff(25), *G1b = ff(26), *G2w = ff(27), *G2b = ff(28), *Wreg = ff(29),
                *breg = ff(30);

    const int N = in_sizes[0] / 128;  // 40000
    const int E = in_sizes[2] / 2;    // 640000

    char* ws = (char*)d_ws;
    float*  bufA    = (float*)(ws);              // [N,128]
    float*  bufB    = (float*)(ws + 20480000);   // [N,128]
    float*  bufH    = (float*)(ws + 40960000);   // [N,128]
    int2*   elist   = (int2*)(ws + 61440000);    // [E] (src, edge_id)
    int*    row_ptr = (int*)(ws + 66560000);     // [N]
    int*    deg     = (int*)(ws + 66720000);     // [N]
    int*    cursor  = (int*)(ws + 66880000);     // [N]
    int*    excl    = (int*)(ws + 67040000);     // [N]
    int*    parts   = (int*)(ws + 67200000);     // [<=256]
    float*  gate    = (float*)(ws + 67204096);   // [N]
    float*  pooled  = (float*)(ws + 67364096);   // [64,64]
    float*  eebuf   = (float*)(ws + 67380480);   // chunked ee[slots,HC], tail of workspace
    size_t avail = ws_size > (size_t)67380480 ? ws_size - (size_t)67380480 : 0;
    const bool newpath = avail >= ((size_t)64 << 20);   // >=64MB tail -> chunked ee path

    auto cdiv = [](int a, int b) { return (a + b - 1) / b; };
    const int NB = cdiv(N, 256);
    const dim3 gemmG(N / 64, 2);

    // ---- CSR build (once; graph shared by all 3 layers) ----
    k_fill<<<NB, 256, 0, stream>>>((unsigned*)deg, N, 0u);
    k_hist<<<cdiv(E, 256), 256, 0, stream>>>(ei, E, deg);
    k_scan_blocks<<<NB, 256, 0, stream>>>(deg, N, excl, parts);
    k_scan_parts<<<1, 256, 0, stream>>>(parts, NB);
    k_scan_add<<<NB, 256, 0, stream>>>(excl, parts, row_ptr, cursor, N);
    k_scatter<<<cdiv(E, 256), 256, 0, stream>>>(ei, E, cursor, elist);

    if (newpath) {
        // ---- layer 1 ----
        k_gemm2<128, 8><<<gemmG, 256, 0, stream>>>(x, W1l, b1l, W1r, b1r, bufA, bufB);
        launch_layer_agg<2, true>(ea, elist, row_ptr, deg, W1e, att1, bias1, bufA, bufB, bufH, eebuf, avail, N, E, stream);
        // ---- layer 2 ----
        k_gemm2<128, 8><<<gemmG, 256, 0, stream>>>(bufH, W2l, b2l, W2r, b2r, bufA, bufB);
        launch_layer_agg<2, true>(ea, elist, row_ptr, deg, W2e, att2, bias2, bufA, bufB, bufH, eebuf, avail, N, E, stream);
        // ---- layer 3 ----
        k_gemm2<64, 4><<<gemmG, 256, 0, stream>>>(bufH, W3l, b3l, W3r, b3r, bufA, bufB);
        launch_layer_agg<1, false>(ea, elist, row_ptr, deg, W3e, att3, bias3, bufA, bufB, bufH, eebuf, avail, N, E, stream);
    } else {
        const int AGGB = cdiv(N, 4);
        k_gemm2<128, 8><<<gemmG, 256, 0, stream>>>(x, W1l, b1l, W1r, b1r, bufA, bufB);
        k_agg_fb<2, true><<<AGGB, 256, 0, stream>>>(bufA, bufB, ea, elist, row_ptr, deg, W1e, att1, bias1, bufH, N);
        k_gemm2<128, 8><<<gemmG, 256, 0, stream>>>(bufH, W2l, b2l, W2r, b2r, bufA, bufB);
        k_agg_fb<2, true><<<AGGB, 256, 0, stream>>>(bufA, bufB, ea, elist, row_ptr, deg, W2e, att2, bias2, bufH, N);
        k_gemm2<64, 4><<<gemmG, 256, 0, stream>>>(bufH, W3l, b3l, W3r, b3r, bufA, bufB);
        k_agg_fb<1, false><<<AGGB, 256, 0, stream>>>(bufA, bufB, ea, elist, row_ptr, deg, W3e, att3, bias3, bufH, N);
    }

    // ---- attentional pooling + regressor ----
    k_gate<<<N / 64, 256, 0, stream>>>(bufH, G1w, G1b, G2w, G2b, gate, N);
    k_pool<<<64, 256, 0, stream>>>(bufH, gate, batch, pooled, N);
    k_final<<<1, 64, 0, stream>>>(pooled, Wreg, breg, (float*)d_out);
}

// Round 8
// 1067.483 us; speedup vs baseline: 1.8570x; 1.2914x over previous
//
#include <hip/hip_runtime.h>

__global__ void k_fill(unsigned* p, int n, unsigned v) {
    int i = blockIdx.x * blockDim.x + threadIdx.x;
    if (i < n) p[i] = v;
}

// ---------------- CSR build (graph identical across layers; built once) ----------------
__global__ void k_hist(const int* __restrict__ ei, int E, int* __restrict__ deg) {
    int e = blockIdx.x * blockDim.x + threadIdx.x;
    if (e < E) atomicAdd(&deg[ei[E + e]], 1);
}

__global__ void k_scan_blocks(const int* __restrict__ deg, int N,
                              int* __restrict__ excl, int* __restrict__ parts) {
    __shared__ int s[256];
    int t = threadIdx.x, i = blockIdx.x * 256 + t;
    int v = (i < N) ? deg[i] : 0;
    s[t] = v;
    __syncthreads();
    int acc = v;
    for (int off = 1; off < 256; off <<= 1) {
        int add = (t >= off) ? s[t - off] : 0;
        __syncthreads();
        acc += add;
        s[t] = acc;
        __syncthreads();
    }
    if (i < N) excl[i] = acc - v;
    if (t == 255) parts[blockIdx.x] = acc;
}

__global__ void k_scan_parts(int* __restrict__ parts, int nb) {
    __shared__ int s[256];
    int t = threadIdx.x;
    int v = (t < nb) ? parts[t] : 0;
    s[t] = v;
    __syncthreads();
    int acc = v;
    for (int off = 1; off < 256; off <<= 1) {
        int add = (t >= off) ? s[t - off] : 0;
        __syncthreads();
        acc += add;
        s[t] = acc;
        __syncthreads();
    }
    if (t < nb) parts[t] = acc - v;
}

__global__ void k_scan_add(const int* __restrict__ excl, const int* __restrict__ parts,
                           int* __restrict__ row_ptr, int* __restrict__ cursor, int N) {
    int i = blockIdx.x * blockDim.x + threadIdx.x;
    if (i >= N) return;
    int r = excl[i] + parts[i >> 8];
    row_ptr[i] = r;
    cursor[i] = r;
}

__global__ void k_scatter(const int* __restrict__ ei, int E, int* __restrict__ cursor,
                          int2* __restrict__ elist) {
    int e = blockIdx.x * blockDim.x + threadIdx.x;
    if (e >= E) return;
    int d = ei[E + e];
    int j = atomicAdd(&cursor[d], 1);
    elist[j] = make_int2(ei[e], e);
}

// permute edge_attr into CSR order: ea_s[j] = ea[elist[j].y]  (8 threads per edge)
// One-time 82 MB gather; all 3 layers then read ea_s as a pure linear stream.
__global__ void k_reorder(const int2* __restrict__ elist, const float* __restrict__ ea, int E,
                          float4* __restrict__ ea_s) {
    int idx = blockIdx.x * blockDim.x + threadIdx.x;
    int j = idx >> 3, q = idx & 7;
    if (j >= E) return;
    ea_s[(size_t)j * 8 + q] = ((const float4*)ea)[(size_t)elist[j].y * 8 + q];
}

// ---------------- Dual GEMM: out{l,r} = A @ W{l,r} + b{l,r} ----------------
template <int M, int RW>
__global__ __launch_bounds__(256) void k_gemm2(const float* __restrict__ A,
                                               const float* __restrict__ Wl, const float* __restrict__ bl,
                                               const float* __restrict__ Wr, const float* __restrict__ br,
                                               float* __restrict__ outl, float* __restrict__ outr) {
    constexpr int TX = M / 4;
    __shared__ float sA[32][68];
    __shared__ float sW[32][M];
    const float* W    = blockIdx.y ? Wr : Wl;
    const float* bias = blockIdx.y ? br : bl;
    float* out        = blockIdx.y ? outr : outl;
    int t = threadIdx.x;
    int tx = t % TX, ty = t / TX;
    int r0 = blockIdx.x * 64;
    float acc[RW][4] = {};
    for (int kt = 0; kt < 128; kt += 32) {
        for (int l = t; l < 512; l += 256) {
            int row = l >> 3, kq = (l & 7) << 2;
            float4 a = *(const float4*)&A[(size_t)(r0 + row) * 128 + kt + kq];
            sA[kq + 0][row] = a.x; sA[kq + 1][row] = a.y;
            sA[kq + 2][row] = a.z; sA[kq + 3][row] = a.w;
        }
        for (int l = t; l < 32 * M / 4; l += 256) {
            int kk = (l * 4) / M, cc = (l * 4) % M;
            *(float4*)&sW[kk][cc] = *(const float4*)&W[(size_t)(kt + kk) * M + cc];
        }
        __syncthreads();
#pragma unroll
        for (int k = 0; k < 32; k++) {
            float4 w = *(float4*)&sW[k][tx * 4];
            float ar[RW];
#pragma unroll
            for (int i = 0; i < RW; i += 4) {
                float4 a = *(float4*)&sA[k][ty * RW + i];
                ar[i] = a.x; ar[i + 1] = a.y; ar[i + 2] = a.z; ar[i + 3] = a.w;
            }
#pragma unroll
            for (int i = 0; i < RW; i++) {
                acc[i][0] += ar[i] * w.x; acc[i][1] += ar[i] * w.y;
                acc[i][2] += ar[i] * w.z; acc[i][3] += ar[i] * w.w;
            }
        }
        __syncthreads();
    }
    float4 b = *(const float4*)&bias[tx * 4];
#pragma unroll
    for (int i = 0; i < RW; i++) {
        float4 v;
        v.x = acc[i][0] + b.x; v.y = acc[i][1] + b.y;
        v.z = acc[i][2] + b.z; v.w = acc[i][3] + b.w;
        *(float4*)&out[(size_t)(r0 + ty * RW + i) * M + tx * 4] = v;
    }
}

// ---------------- Edge transform GEMM (v8, pure stream): ee[slot] = ea_s[slot] @ We ----
// Input ea_s is CSR-ordered (k_reorder) -> NO gathers anywhere in this kernel.
// 128 slots/block staged to LDS (16 KB) with 4 coalesced float4 loads per thread.
// Each thread owns a column PAIR (register float2 We column, r0-agg style -> low VGPR),
// reads the ea row via broadcast LDS b128, writes ee as coalesced float2.
// VMEM wave-instrs per slot ~2.3 (vs ~10 effective in the gather version).
template <int HC>
__global__ __launch_bounds__(256) void k_edge_gemm(const float* __restrict__ ea_s,
                                                   const int* __restrict__ row_ptr,
                                                   const float* __restrict__ We,
                                                   float* __restrict__ ee,
                                                   int n0, int n1, int Ntot, int E) {
    constexpr int SLOTS = 128;
    constexpr int CP = HC / 2;        // threads per slot-row (64 or 32)
    constexpr int RG = 256 / CP;      // row groups per block (4 or 8)
    int s0 = row_ptr[n0];
    int s1 = (n1 >= Ntot) ? E : row_ptr[n1];
    int sb = s0 + blockIdx.x * SLOTS;
    if (sb >= s1) return;
    __shared__ float sE[SLOTS * 32];  // 16 KB
    int t = threadIdx.x;
    {   // stage SLOTS*8 = 1024 float4, linear & coalesced: 4 per thread
        const float4* g4 = (const float4*)ea_s;
        float4* s4 = (float4*)sE;
        size_t b4 = (size_t)sb * 8;
        size_t lim = (size_t)E * 8;
#pragma unroll
        for (int l = 0; l < 4; l++) {
            int idx = t + l * 256;
            size_t g = b4 + idx;
            s4[idx] = (g < lim) ? g4[g] : make_float4(0.f, 0.f, 0.f, 0.f);
        }
    }
    int c2 = t % CP, rg = t / CP;
    int col = 2 * c2;
    float2 rWe[32];
#pragma unroll
    for (int k = 0; k < 32; k++) rWe[k] = *(const float2*)&We[k * HC + col];
    __syncthreads();
    for (int i = 0; i < SLOTS / RG; i++) {
        int sl = i * RG + rg;
        int s = sb + sl;
        if (s >= s1) continue;
        const float* er = &sE[sl * 32];
        float ax = 0.f, ay = 0.f, bx = 0.f, by = 0.f;   // two chains per channel
#pragma unroll
        for (int k = 0; k < 32; k += 4) {
            float4 a = *(const float4*)&er[k];          // broadcast ds_read_b128
            ax = fmaf(a.x, rWe[k].x, ax);     ay = fmaf(a.x, rWe[k].y, ay);
            ax = fmaf(a.y, rWe[k + 1].x, ax); ay = fmaf(a.y, rWe[k + 1].y, ay);
            bx = fmaf(a.z, rWe[k + 2].x, bx); by = fmaf(a.z, rWe[k + 2].y, by);
            bx = fmaf(a.w, rWe[k + 3].x, bx); by = fmaf(a.w, rWe[k + 3].y, by);
        }
        *(float2*)&ee[(size_t)(s - s0) * HC + col] = make_float2(ax + bx, ay + by);
    }
}

// ---------------- Lean fused GATv2 aggregation (uses precomputed ee) ----------------
// Proven round-3 structure: 3 VMEM instrs/visit, 2-deep pipeline, float2 per lane.
template <int H, bool RELU>
__global__ __launch_bounds__(256) void k_aggv(const float* __restrict__ xl, const float* __restrict__ xr,
                                              const float* __restrict__ ee,
                                              const int2* __restrict__ elist,
                                              const int* __restrict__ row_ptr, const int* __restrict__ deg,
                                              const float* __restrict__ att, const float* __restrict__ bias,
                                              float* __restrict__ out, int n0, int n1) {
    constexpr int HC = H * 64;
    __shared__ float2 sAcc[2][64];
    __shared__ float  sDen[2][64];
    int tid = threadIdx.x, wv = tid >> 6, lane = tid & 63;
    int ns = wv >> 1, eh = wv & 1;
    int n = n0 + blockIdx.x * 2 + ns;
    bool alive = n < n1;
    int hf = lane >> 5, c2 = lane & 31;
    int col = (H == 2) ? (hf * 64 + 2 * c2) : (2 * c2);
    float2 attv = *(const float2*)&att[col];
    int s0 = row_ptr[n0];
    float2 xrv = make_float2(0.f, 0.f);
    int start = 0, d = 0;
    if (alive) {
        xrv = *(const float2*)&xr[(size_t)n * HC + col];
        start = row_ptr[n];
        d = deg[n];
    }
    float2 acc = make_float2(0.f, 0.f);
    float den = 0.f;

    const int jstep = (H == 2) ? 2 : 4;
    int jc = (H == 2) ? eh : (2 * eh + hf);
    bool okc = jc < d;
    int sC = start + jc;
    int sN = sC + jstep;
    int spx = okc ? elist[sC].x : 0;
    float2 eeC = okc ? *(const float2*)&ee[(size_t)(sC - s0) * HC + col] : make_float2(0.f, 0.f);
    float2 xlC = okc ? *(const float2*)&xl[(size_t)spx * HC + col] : make_float2(0.f, 0.f);
    bool okn = (jc + jstep) < d;
    int spxN = okn ? elist[sN].x : 0;

    while (okc) {
        bool okn2 = (jc + 2 * jstep) < d;
        int sN2 = sN + jstep;
        int spxN2 = okn2 ? elist[sN2].x : 0;
        float2 eeN = okn ? *(const float2*)&ee[(size_t)(sN - s0) * HC + col] : make_float2(0.f, 0.f);
        float2 xlN = okn ? *(const float2*)&xl[(size_t)spxN * HC + col] : make_float2(0.f, 0.f);

        float v0 = xlC.x + xrv.x + eeC.x;
        float v1 = xlC.y + xrv.y + eeC.y;
        v0 = v0 > 0.f ? v0 : 0.2f * v0;
        v1 = v1 > 0.f ? v1 : 0.2f * v1;
        float p = fmaf(attv.x, v0, attv.y * v1);
#pragma unroll
        for (int m = 16; m; m >>= 1) p += __shfl_xor(p, m);
        float ex = __expf(p);
        acc.x = fmaf(ex, xlC.x, acc.x);
        acc.y = fmaf(ex, xlC.y, acc.y);
        den += ex;

        jc += jstep; sC = sN; sN = sN2;
        xlC = xlN; eeC = eeN; spxN = spxN2;
        okc = okn; okn = okn2;
    }

    if constexpr (H == 1) {
        acc.x += __shfl_xor(acc.x, 32);
        acc.y += __shfl_xor(acc.y, 32);
        den   += __shfl_xor(den, 32);
    }
    if (eh == 1) { sAcc[ns][lane] = acc; sDen[ns][lane] = den; }
    __syncthreads();
    if (eh == 0 && alive) {
        float2 a = sAcc[ns][lane];
        float dd = sDen[ns][lane];
        float dsum = den + dd + 1e-16f;
        float2 bv = *(const float2*)&bias[col];
        float o0 = (acc.x + a.x) / dsum + bv.x;
        float o1 = (acc.y + a.y) / dsum + bv.y;
        if (RELU) { o0 = fmaxf(o0, 0.f); o1 = fmaxf(o1, 0.f); }
        if (H == 2 || hf == 0)
            *(float2*)&out[(size_t)n * HC + col] = make_float2(o0, o1);
    }
}

// ---------------- Fallback agg (round-0 structure, unsorted ea) — tiny-workspace path ----
template <int H, bool RELU>
__global__ __launch_bounds__(256) void k_agg_fb(const float* __restrict__ xl, const float* __restrict__ xr,
                                                const float* __restrict__ ea,
                                                const int2* __restrict__ elist,
                                                const int* __restrict__ row_ptr, const int* __restrict__ deg,
                                                const float* __restrict__ We, const float* __restrict__ att,
                                                const float* __restrict__ bias, float* __restrict__ out, int N) {
    constexpr int HC = H * 64;
    int tid = threadIdx.x, wv = tid >> 6, lane = tid & 63;
    float rWe0[32], rWe1[H == 2 ? 32 : 1];
#pragma unroll
    for (int k = 0; k < 32; k++) rWe0[k] = We[k * HC + lane];
    if constexpr (H == 2) {
#pragma unroll
        for (int k = 0; k < 32; k++) rWe1[k] = We[k * HC + 64 + lane];
    }
    float att0 = att[lane], b0 = bias[lane];
    float att1 = 0.f, b1 = 0.f;
    if constexpr (H == 2) { att1 = att[64 + lane]; b1 = bias[64 + lane]; }
    int n = blockIdx.x * 4 + wv;
    if (n >= N) return;
    int start = row_ptr[n], d = deg[n];
    float xr0 = xr[(size_t)n * HC + lane];
    float xr1 = (H == 2) ? xr[(size_t)n * HC + 64 + lane] : 0.f;
    float acc0 = 0.f, acc1 = 0.f, den0 = 0.f, den1 = 0.f;
    for (int j = 0; j < d; j++) {
        int2 sp = elist[start + j];
        const float4* eap = (const float4*)(ea + (size_t)sp.y * 32);
        const float* xls = xl + (size_t)sp.x * HC;
        float xl0 = xls[lane];
        float xl1 = (H == 2) ? xls[64 + lane] : 0.f;
        float ee0 = 0.f, ee1 = 0.f;
#pragma unroll
        for (int kq = 0; kq < 8; kq++) {
            float4 v = eap[kq];
            ee0 = fmaf(v.x, rWe0[kq * 4 + 0], ee0);
            ee0 = fmaf(v.y, rWe0[kq * 4 + 1], ee0);
            ee0 = fmaf(v.z, rWe0[kq * 4 + 2], ee0);
            ee0 = fmaf(v.w, rWe0[kq * 4 + 3], ee0);
            if constexpr (H == 2) {
                ee1 = fmaf(v.x, rWe1[kq * 4 + 0], ee1);
                ee1 = fmaf(v.y, rWe1[kq * 4 + 1], ee1);
                ee1 = fmaf(v.z, rWe1[kq * 4 + 2], ee1);
                ee1 = fmaf(v.w, rWe1[kq * 4 + 3], ee1);
            }
        }
        float v0 = xl0 + xr0 + ee0;
        v0 = v0 > 0.f ? v0 : 0.2f * v0;
        float p0 = att0 * v0, p1 = 0.f;
        if constexpr (H == 2) {
            float v1 = xl1 + xr1 + ee1;
            v1 = v1 > 0.f ? v1 : 0.2f * v1;
            p1 = att1 * v1;
        }
#pragma unroll
        for (int m = 32; m; m >>= 1) {
            p0 += __shfl_xor(p0, m);
            if constexpr (H == 2) p1 += __shfl_xor(p1, m);
        }
        float ex0 = __expf(p0);
        acc0 = fmaf(ex0, xl0, acc0);
        den0 += ex0;
        if constexpr (H == 2) {
            float ex1 = __expf(p1);
            acc1 = fmaf(ex1, xl1, acc1);
            den1 += ex1;
        }
    }
    float o0 = acc0 / (den0 + 1e-16f) + b0;
    if (RELU) o0 = o0 > 0.f ? o0 : 0.f;
    out[(size_t)n * HC + lane] = o0;
    if constexpr (H == 2) {
        float o1 = acc1 / (den1 + 1e-16f) + b1;
        if (RELU) o1 = o1 > 0.f ? o1 : 0.f;
        out[(size_t)n * HC + 64 + lane] = o1;
    }
}

// ---------------- gate MLP ----------------
__global__ __launch_bounds__(256) void k_gate(const float* __restrict__ h, const float* __restrict__ G1w,
                                              const float* __restrict__ G1b, const float* __restrict__ G2w,
                                              const float* __restrict__ G2b,
                                              float* __restrict__ gate, int N) {
    __shared__ float sH[64][64];
    __shared__ float part[64][2];
    int t = threadIdx.x;
    int n0 = blockIdx.x * 64;
    for (int l = t; l < 1024; l += 256) {
        float4 v = ((const float4*)(h + (size_t)n0 * 64))[l];
        int n = l >> 4, kq = (l & 15) << 2;
        *(float4*)&sH[n][kq] = v;
    }
    int c = t & 127, half = t >> 7;
    float rW[64];
#pragma unroll
    for (int k = 0; k < 64; k++) rW[k] = G1w[k * 128 + c];
    float g1b = G1b[c], g2w = G2w[c];
    __syncthreads();
    for (int nn = 0; nn < 32; nn++) {
        int n = half * 32 + nn;
        float acc = g1b;
#pragma unroll
        for (int k = 0; k < 64; k += 4) {
            float4 hv = *(const float4*)&sH[n][k];
            acc = fmaf(hv.x, rW[k], acc);
            acc = fmaf(hv.y, rW[k + 1], acc);
            acc = fmaf(hv.z, rW[k + 2], acc);
            acc = fmaf(hv.w, rW[k + 3], acc);
        }
        acc = acc > 0.f ? acc : 0.f;
        float p = acc * g2w;
#pragma unroll
        for (int m = 32; m; m >>= 1) p += __shfl_xor(p, m);
        if ((t & 63) == 0) part[n][(t >> 6) & 1] = p;
    }
    __syncthreads();
    if (t < 64) gate[n0 + t] = __expf(part[t][0] + part[t][1] + G2b[0]);
}

// ---------------- pooling ----------------
__global__ __launch_bounds__(256) void k_pool(const float* __restrict__ h, const float* __restrict__ gate,
                                              const int* __restrict__ batch,
                                              float* __restrict__ pooled, int N) {
    int g = blockIdx.x;
    int lo = 0, hi = N;
    while (lo < hi) { int mid = (lo + hi) >> 1; if (batch[mid] < g) lo = mid + 1; else hi = mid; }
    int start = lo;
    lo = 0; hi = N;
    while (lo < hi) { int mid = (lo + hi) >> 1; if (batch[mid] < g + 1) lo = mid + 1; else hi = mid; }
    int end = lo;
    int t = threadIdx.x, wv = t >> 6, lane = t & 63;
    float acc = 0.f, den = 0.f;
    for (int n = start + wv; n < end; n += 4) {
        float gv = gate[n];
        acc = fmaf(gv, h[(size_t)n * 64 + lane], acc);
        den += gv;
    }
    __shared__ float sacc[4][64];
    __shared__ float sden[4];
    sacc[wv][lane] = acc;
    if (lane == 0) sden[wv] = den;
    __syncthreads();
    if (wv == 0) {
        float a = sacc[0][lane] + sacc[1][lane] + sacc[2][lane] + sacc[3][lane];
        float d = sden[0] + sden[1] + sden[2] + sden[3] + 1e-16f;
        pooled[g * 64 + lane] = a / d;
    }
}

__global__ void k_final(const float* __restrict__ pooled, const float* __restrict__ Wreg,
                        const float* __restrict__ breg, float* __restrict__ out) {
    int g = threadIdx.x;
    float acc = breg[0];
    for (int c = 0; c < 64; c++) acc += pooled[g * 64 + c] * Wreg[c];
    out[g] = acc;
}

// ---------------- host-side per-layer chunked launch ----------------
template <int H, bool RELU>
static void launch_layer_agg(const float* ea_s, const int2* elist, const int* row_ptr, const int* deg,
                             const float* We, const float* att, const float* bias,
                             const float* xl, const float* xr, float* outb, float* eebuf,
                             size_t avail, int N, int E, hipStream_t stream) {
    constexpr int HC = H * 64;
    size_t need = (size_t)E * HC * 4;
    int K = (avail >= need) ? 1 : (int)((need * 21 / 20 + avail - 1) / avail);
    size_t cap_slots = (K == 1) ? (size_t)E : avail / ((size_t)HC * 4);
    size_t cover = cap_slots < (size_t)E ? cap_slots : (size_t)E;
    int gb = (int)((cover + 127) / 128);
    for (int c = 0; c < K; c++) {
        int n0 = (int)((long long)N * c / K);
        int n1 = (int)((long long)N * (c + 1) / K);
        k_edge_gemm<HC><<<gb, 256, 0, stream>>>(ea_s, row_ptr, We, eebuf, n0, n1, N, E);
        int nb = (n1 - n0 + 1) / 2;
        k_aggv<H, RELU><<<nb, 256, 0, stream>>>(xl, xr, eebuf, elist, row_ptr, deg, att, bias, outb, n0, n1);
    }
}

extern "C" void kernel_launch(void* const* d_in, const int* in_sizes, int n_in,
                              void* d_out, int out_size, void* d_ws, size_t ws_size,
                              hipStream_t stream) {
    const float* x  = (const float*)d_in[0];
    const float* ea = (const float*)d_in[1];
    const int* ei    = (const int*)d_in[2];
    const int* batch = (const int*)d_in[3];
    auto ff = [&](int i) { return (const float*)d_in[i]; };
    const float *W1l = ff(4), *b1l = ff(5), *W1r = ff(6), *b1r = ff(7), *W1e = ff(8),
                *att1 = ff(9), *bias1 = ff(10);
    const float *W2l = ff(11), *b2l = ff(12), *W2r = ff(13), *b2r = ff(14), *W2e = ff(15),
                *att2 = ff(16), *bias2 = ff(17);
    const float *W3l = ff(18), *b3l = ff(19), *W3r = ff(20), *b3r = ff(21), *W3e = ff(22),
                *att3 = ff(23), *bias3 = ff(24);
    const float *G1w = ff(25), *G1b = ff(26), *G2w = ff(27), *G2b = ff(28), *Wreg = ff(29),
                *breg = ff(30);

    const int N = in_sizes[0] / 128;  // 40000
    const int E = in_sizes[2] / 2;    // 640000

    char* ws = (char*)d_ws;
    float*  bufA    = (float*)(ws);              // [N,128]
    float*  bufB    = (float*)(ws + 20480000);   // [N,128]
    float*  bufH    = (float*)(ws + 40960000);   // [N,128]
    int2*   elist   = (int2*)(ws + 61440000);    // [E] (src, edge_id)
    int*    row_ptr = (int*)(ws + 66560000);     // [N]
    int*    deg     = (int*)(ws + 66720000);     // [N]
    int*    cursor  = (int*)(ws + 66880000);     // [N]
    int*    excl    = (int*)(ws + 67040000);     // [N]
    int*    parts   = (int*)(ws + 67200000);     // [<=256]
    float*  gate    = (float*)(ws + 67204096);   // [N]
    float*  pooled  = (float*)(ws + 67364096);   // [64,64]
    float*  ea_s    = (float*)(ws + 67380480);   // [E,32] floats, CSR-ordered (82 MB)
    size_t  ea_s_end = (size_t)67380480 + (size_t)E * 32 * 4;
    float*  eebuf   = (float*)(ws + ea_s_end);   // chunked ee[slots,HC]
    size_t avail_ee = ws_size > ea_s_end ? ws_size - ea_s_end : 0;
    const bool newpath = avail_ee >= ((size_t)64 << 20);   // ea_s + >=64MB ee tail

    auto cdiv = [](int a, int b) { return (a + b - 1) / b; };
    const int NB = cdiv(N, 256);
    const dim3 gemmG(N / 64, 2);

    // ---- CSR build (once; graph shared by all 3 layers) ----
    k_fill<<<NB, 256, 0, stream>>>((unsigned*)deg, N, 0u);
    k_hist<<<cdiv(E, 256), 256, 0, stream>>>(ei, E, deg);
    k_scan_blocks<<<NB, 256, 0, stream>>>(deg, N, excl, parts);
    k_scan_parts<<<1, 256, 0, stream>>>(parts, NB);
    k_scan_add<<<NB, 256, 0, stream>>>(excl, parts, row_ptr, cursor, N);
    k_scatter<<<cdiv(E, 256), 256, 0, stream>>>(ei, E, cursor, elist);

    if (newpath) {
        k_reorder<<<cdiv(E * 8, 256), 256, 0, stream>>>(elist, ea, E, (float4*)ea_s);
        // ---- layer 1 ----
        k_gemm2<128, 8><<<gemmG, 256, 0, stream>>>(x, W1l, b1l, W1r, b1r, bufA, bufB);
        launch_layer_agg<2, true>(ea_s, elist, row_ptr, deg, W1e, att1, bias1, bufA, bufB, bufH, eebuf, avail_ee, N, E, stream);
        // ---- layer 2 ----
        k_gemm2<128, 8><<<gemmG, 256, 0, stream>>>(bufH, W2l, b2l, W2r, b2r, bufA, bufB);
        launch_layer_agg<2, true>(ea_s, elist, row_ptr, deg, W2e, att2, bias2, bufA, bufB, bufH, eebuf, avail_ee, N, E, stream);
        // ---- layer 3 ----
        k_gemm2<64, 4><<<gemmG, 256, 0, stream>>>(bufH, W3l, b3l, W3r, b3r, bufA, bufB);
        launch_layer_agg<1, false>(ea_s, elist, row_ptr, deg, W3e, att3, bias3, bufA, bufB, bufH, eebuf, avail_ee, N, E, stream);
    } else {
        const int AGGB = cdiv(N, 4);
        k_gemm2<128, 8><<<gemmG, 256, 0, stream>>>(x, W1l, b1l, W1r, b1r, bufA, bufB);
        k_agg_fb<2, true><<<AGGB, 256, 0, stream>>>(bufA, bufB, ea, elist, row_ptr, deg, W1e, att1, bias1, bufH, N);
        k_gemm2<128, 8><<<gemmG, 256, 0, stream>>>(bufH, W2l, b2l, W2r, b2r, bufA, bufB);
        k_agg_fb<2, true><<<AGGB, 256, 0, stream>>>(bufA, bufB, ea, elist, row_ptr, deg, W2e, att2, bias2, bufH, N);
        k_gemm2<64, 4><<<gemmG, 256, 0, stream>>>(bufH, W3l, b3l, W3r, b3r, bufA, bufB);
        k_agg_fb<1, false><<<AGGB, 256, 0, stream>>>(bufA, bufB, ea, elist, row_ptr, deg, W3e, att3, bias3, bufH, N);
    }

    // ---- attentional pooling + regressor ----
    k_gate<<<N / 64, 256, 0, stream>>>(bufH, G1w, G1b, G2w, G2b, gate, N);
    k_pool<<<64, 256, 0, stream>>>(bufH, gate, batch, pooled, N);
    k_final<<<1, 64, 0, stream>>>(pooled, Wreg, breg, (float*)d_out);
}